// Round 2
// baseline (3906.647 us; speedup 1.0000x reference)
//
#include <hip/hip_runtime.h>

#define R_    16
#define NBAS  30
#define DIN1  128
#define DHID  128
#define DOUT2 64
#define DADR  400

typedef __attribute__((ext_vector_type(8))) short bf16x8;
typedef __attribute__((ext_vector_type(4))) float f32x4;

__device__ __forceinline__ short f2bf(float f) {
    unsigned u = __float_as_uint(f);
    u += 0x7fffu + ((u >> 16) & 1u);   // round-to-nearest-even
    return (short)(u >> 16);
}

// ---------------- count edges per (dst, relation) bucket ----------------
__global__ __launch_bounds__(256) void count_kernel(const int* __restrict__ dst,
                                                    const int* __restrict__ ety,
                                                    float* __restrict__ cnt, int E) {
    int e = blockIdx.x * blockDim.x + threadIdx.x;
    if (e < E) atomicAdd(&cnt[dst[e] * R_ + ety[e]], 1.0f);
}

// ------- wT[o][r*DIN + i] = bf16( sum_b comp[r,b] * basis[b,i,o] ) -------
__global__ __launch_bounds__(256) void weightsT_kernel(const float* __restrict__ comp,
                                                       const float* __restrict__ basis,
                                                       short* __restrict__ wT,
                                                       int DIN, int DOUT, int ldb) {
    int idx = blockIdx.x * blockDim.x + threadIdx.x;
    int total = R_ * DIN * DOUT;
    if (idx >= total) return;
    int o = idx % DOUT;
    int i = (idx / DOUT) % DIN;
    int r = idx / (DOUT * DIN);
    float acc = 0.f;
    #pragma unroll 6
    for (int b = 0; b < NBAS; ++b)
        acc += comp[r * NBAS + b] * basis[((size_t)b * DIN + i) * DOUT + o];
    wT[(size_t)o * ldb + r * DIN + i] = f2bf(acc);
}

// ------- rT[o][i] = bf16(root[i][o]) -------
__global__ __launch_bounds__(256) void transposeT_kernel(const float* __restrict__ root,
                                                         short* __restrict__ rT,
                                                         int DIN, int DOUT) {
    int idx = blockIdx.x * blockDim.x + threadIdx.x;
    if (idx >= DIN * DOUT) return;
    int o = idx % DOUT;
    int i = idx / DOUT;
    rT[(size_t)o * DIN + i] = f2bf(root[(size_t)i * DOUT + o]);
}

// ------- scatter: agg[(dst*R+ety)*CHT + j] += feat[src][c0+j], float4 per thread -------
template<int CHT>
__global__ __launch_bounds__(256) void scatter_kernel(const float* __restrict__ feat,
                                                      const int* __restrict__ src,
                                                      const int* __restrict__ dst,
                                                      const int* __restrict__ ety,
                                                      float* __restrict__ agg,
                                                      int E, int featDim, int c0) {
    constexpr int J = CHT / 4;
    long long t = (long long)blockIdx.x * 256 + threadIdx.x;
    int e = (int)(t / J);
    int j = (int)(t % J);
    if (e >= E) return;
    int s   = src[e];
    int seg = dst[e] * R_ + ety[e];
    float4 v = *(const float4*)(feat + (size_t)s * featDim + c0 + j * 4);
    float* p = agg + (size_t)seg * CHT + j * 4;
    atomicAdd(p + 0, v.x);
    atomicAdd(p + 1, v.y);
    atomicAdd(p + 2, v.z);
    atomicAdd(p + 3, v.w);
}

// ------- MFMA GEMM: H[n][o] (+)= sum_k scale(n,k) * A[n][k] * BT[o][map(k)]
//   scale(n,k) = 1/max(cnt[n*R + (k>>lgCHT)],1) if cnt else 1
//   map(k0)    = (k0>>lgCHT)*DINp + c0 + (k0 & (CHT-1))   (uniform per BK-step)
//   flags&1: init (add bias, no prev read)   flags&2: relu -------
template<int BN, int BK>
__global__ __launch_bounds__(256)
void gemm_kernel(const float* __restrict__ A, int lda,
                 const float* __restrict__ cnt, int lgCHT, int c0, int DINp,
                 const short* __restrict__ BT, int ldb, int Ktot,
                 const float* __restrict__ bias,
                 float* __restrict__ H, int N, int flags)
{
    constexpr int BM  = 128;
    constexpr int WGN = (BN == 128) ? 2 : 1;
    constexpr int WGM = 4 / WGN;
    constexpr int WM  = BM / WGM;          // 64 or 32
    constexpr int WN  = BN / WGN;          // 64
    constexpr int MR  = WM / 16;           // 4 or 2
    constexpr int NR  = WN / 16;           // 4
    constexpr int SWM = BK / 8 - 1;        // swizzle row mask (stay inside row)

    __shared__ short lA[BM * BK];
    __shared__ short lB[BN * BK];

    const int tid  = threadIdx.x;
    const int lane = tid & 63;
    const int wv   = tid >> 6;
    const int wr   = wv / WGN;
    const int wcc  = wv % WGN;
    const int nodeBase = blockIdx.x * BM;

    f32x4 acc[MR][NR];
    #pragma unroll
    for (int m = 0; m < MR; ++m)
        #pragma unroll
        for (int n = 0; n < NR; ++n)
            acc[m][n] = (f32x4){0.f, 0.f, 0.f, 0.f};

    for (int k0 = 0; k0 < Ktot; k0 += BK) {
        const int r    = k0 >> lgCHT;
        const int bcol = r * DINp + c0 + (k0 - (r << lgCHT));

        // ---- A tile: BM x BK f32 -> scaled bf16, swizzled ----
        {
            constexpr int C4  = BK / 4;        // float4 per row
            constexpr int RPI = 256 / C4;      // rows per iteration
            const int c4 = tid % C4;
            const int r0 = tid / C4;
            #pragma unroll
            for (int it = 0; it < BM / RPI; ++it) {
                int row  = r0 + it * RPI;
                int grow = nodeBase + row;
                float4 v = {0.f, 0.f, 0.f, 0.f};
                float  s = 1.0f;
                if (grow < N) {
                    v = *(const float4*)(A + (size_t)grow * lda + k0 + c4 * 4);
                    if (cnt) s = 1.0f / fmaxf(cnt[grow * R_ + r], 1.0f);
                }
                short4 b4 = { f2bf(v.x * s), f2bf(v.y * s), f2bf(v.z * s), f2bf(v.w * s) };
                int byte = ((row * BK + c4 * 4) << 1) ^ ((row & SWM) << 4);
                *(short4*)((char*)lA + byte) = b4;
            }
        }
        // ---- B tile: BN x BK bf16, swizzled (BT is [o][Kfull] row-major) ----
        {
            constexpr int C8  = BK / 8;        // 16B units per row
            constexpr int OPI = 256 / C8;
            const int t8 = tid % C8;
            const int o0 = tid / C8;
            #pragma unroll
            for (int o = o0; o < BN; o += OPI) {
                int4 v = *(const int4*)(BT + (size_t)o * ldb + bcol + t8 * 8);
                int byte = ((o * BK + t8 * 8) << 1) ^ ((o & SWM) << 4);
                *(int4*)((char*)lB + byte) = v;
            }
        }
        __syncthreads();

        #pragma unroll
        for (int kk = 0; kk < BK / 32; ++kk) {
            const int kpos = kk * 32 + (lane >> 4) * 8;
            bf16x8 af[MR], bfr[NR];
            #pragma unroll
            for (int m = 0; m < MR; ++m) {
                int row = wr * WM + m * 16 + (lane & 15);
                af[m] = *(const bf16x8*)((const char*)lA +
                         (((row * BK + kpos) << 1) ^ ((row & SWM) << 4)));
            }
            #pragma unroll
            for (int n = 0; n < NR; ++n) {
                int col = wcc * WN + n * 16 + (lane & 15);
                bfr[n] = *(const bf16x8*)((const char*)lB +
                         (((col * BK + kpos) << 1) ^ ((col & SWM) << 4)));
            }
            #pragma unroll
            for (int m = 0; m < MR; ++m)
                #pragma unroll
                for (int n = 0; n < NR; ++n)
                    acc[m][n] = __builtin_amdgcn_mfma_f32_16x16x32_bf16(
                        af[m], bfr[n], acc[m][n], 0, 0, 0);
        }
        __syncthreads();
    }

    // ---- epilogue: C/D layout row=(lane>>4)*4+i, col=lane&15 ----
    #pragma unroll
    for (int m = 0; m < MR; ++m)
        #pragma unroll
        for (int n = 0; n < NR; ++n)
            #pragma unroll
            for (int i = 0; i < 4; ++i) {
                int row  = wr * WM + m * 16 + ((lane >> 4) << 2) + i;
                int col  = wcc * WN + n * 16 + (lane & 15);
                int grow = nodeBase + row;
                if (grow >= N) continue;
                float v = acc[m][n][i];
                if (flags & 1) v += bias[col];
                else           v += H[(size_t)grow * BN + col];
                if (flags & 2) v = fmaxf(v, 0.f);
                H[(size_t)grow * BN + col] = v;
            }
}

// ------- classifier: out[n][a] = h[n][:] @ wc[:][a] + bc[a], h tile in LDS -------
__global__ __launch_bounds__(256)
void classifier_kernel(const float* __restrict__ h, const float* __restrict__ wc,
                       const float* __restrict__ bc, float* __restrict__ out, int N) {
    constexpr int NB = 32;
    __shared__ float lh[NB * DOUT2];
    const int nb  = blockIdx.x * NB;
    const int tid = threadIdx.x;
    for (int idx = tid; idx < NB * DOUT2; idx += 256) {
        int gn = nb + idx / DOUT2;
        lh[idx] = (gn < N) ? h[(size_t)gn * DOUT2 + (idx % DOUT2)] : 0.f;
    }
    __syncthreads();
    for (int idx = tid; idx < NB * DADR; idx += 256) {
        int nl = idx / DADR, a = idx % DADR;
        int gn = nb + nl;
        if (gn >= N) continue;
        const float* hr = lh + nl * DOUT2;
        float acc = bc[a];
        #pragma unroll 16
        for (int k = 0; k < DOUT2; ++k)
            acc += hr[k] * wc[k * DADR + a];
        out[(size_t)gn * DADR + a] = acc;
    }
}

// ---------------- host-side pipeline ----------------
template<int CHT, int BK>
static void run_pipeline(const float* x, const int* srcp, const int* dstp, const int* et,
                         const float* comp1, const float* basis1, const float* root1, const float* bias1,
                         const float* comp2, const float* basis2, const float* root2, const float* bias2,
                         const float* wc, const float* bc,
                         float* out, char* ws, int N, int E, hipStream_t stream) {
    constexpr int lg = (CHT == 128) ? 7 : (CHT == 64 ? 6 : 5);
    const int Kfull = R_ * DIN1;   // 2048

    float* cnt = (float*)ws;                       size_t off = (size_t)N * R_ * 4;
    float* agg = (float*)(ws + off);               off += (size_t)N * R_ * CHT * 4;
    short* w1T = (short*)(ws + off);               off += (size_t)DHID * Kfull * 2;
    short* w2T = (short*)(ws + off);               off += (size_t)DOUT2 * (R_ * DHID) * 2;
    short* r1T = (short*)(ws + off);               off += (size_t)DHID * DIN1 * 2;
    short* r2T = (short*)(ws + off);               off += (size_t)DOUT2 * DHID * 2;
    float* h1  = (float*)(ws + off);               off += (size_t)N * DHID * 4;
    float* h2  = (float*)(ws + off);

    const size_t aggBytes = (size_t)N * R_ * CHT * 4;

    hipMemsetAsync(cnt, 0, (size_t)N * R_ * 4, stream);
    count_kernel<<<(E + 255) / 256, 256, 0, stream>>>(dstp, et, cnt, E);
    weightsT_kernel<<<(R_ * DIN1 * DHID + 255) / 256, 256, 0, stream>>>(comp1, basis1, w1T, DIN1, DHID, Kfull);
    weightsT_kernel<<<(R_ * DHID * DOUT2 + 255) / 256, 256, 0, stream>>>(comp2, basis2, w2T, DHID, DOUT2, R_ * DHID);
    transposeT_kernel<<<(DIN1 * DHID + 255) / 256, 256, 0, stream>>>(root1, r1T, DIN1, DHID);
    transposeT_kernel<<<(DHID * DOUT2 + 255) / 256, 256, 0, stream>>>(root2, r2T, DHID, DOUT2);

    const int gGrid = (N + 127) / 128;
    const long long sthreads = (long long)E * (CHT / 4);
    const int sGrid = (int)((sthreads + 255) / 256);
    constexpr int NC = DIN1 / CHT;   // chunks (DIN1 == DHID)

    // ---- layer 1: x -> h1 (relu) ----
    gemm_kernel<DHID, BK><<<gGrid, 256, 0, stream>>>(x, DIN1, nullptr, 7, 0, DIN1,
                                                     r1T, DIN1, DIN1, bias1, h1, N, 1);
    for (int c = 0; c < NC; ++c) {
        hipMemsetAsync(agg, 0, aggBytes, stream);
        scatter_kernel<CHT><<<sGrid, 256, 0, stream>>>(x, srcp, dstp, et, agg, E, DIN1, c * CHT);
        int flags = (c == NC - 1) ? 2 : 0;
        gemm_kernel<DHID, BK><<<gGrid, 256, 0, stream>>>(agg, R_ * CHT, cnt, lg, c * CHT, DIN1,
                                                         w1T, Kfull, R_ * CHT, bias1, h1, N, flags);
    }

    // ---- layer 2: h1 -> h2 ----
    gemm_kernel<DOUT2, BK><<<gGrid, 256, 0, stream>>>(h1, DHID, nullptr, 7, 0, DHID,
                                                      r2T, DHID, DHID, bias2, h2, N, 1);
    for (int c = 0; c < NC; ++c) {
        hipMemsetAsync(agg, 0, aggBytes, stream);
        scatter_kernel<CHT><<<sGrid, 256, 0, stream>>>(h1, srcp, dstp, et, agg, E, DHID, c * CHT);
        gemm_kernel<DOUT2, BK><<<gGrid, 256, 0, stream>>>(agg, R_ * CHT, cnt, lg, c * CHT, DHID,
                                                          w2T, R_ * DHID, R_ * CHT, bias2, h2, N, 0);
    }

    // ---- classifier ----
    classifier_kernel<<<(N + 31) / 32, 256, 0, stream>>>(h2, wc, bc, out, N);
}

static size_t ws_needed(int N, int CHT) {
    const int Kfull = R_ * DIN1;
    return (size_t)N * R_ * 4
         + (size_t)N * R_ * CHT * 4
         + (size_t)DHID * Kfull * 2
         + (size_t)DOUT2 * (R_ * DHID) * 2
         + (size_t)DHID * DIN1 * 2
         + (size_t)DOUT2 * DHID * 2
         + (size_t)N * DHID * 4
         + (size_t)N * DOUT2 * 4;
}

extern "C" void kernel_launch(void* const* d_in, const int* in_sizes, int n_in,
                              void* d_out, int out_size, void* d_ws, size_t ws_size,
                              hipStream_t stream) {
    const float* x      = (const float*)d_in[0];
    const int*   ei     = (const int*)d_in[1];
    const int*   et     = (const int*)d_in[2];
    const float* comp1  = (const float*)d_in[3];
    const float* basis1 = (const float*)d_in[4];
    const float* root1  = (const float*)d_in[5];
    const float* bias1  = (const float*)d_in[6];
    const float* comp2  = (const float*)d_in[7];
    const float* basis2 = (const float*)d_in[8];
    const float* root2  = (const float*)d_in[9];
    const float* bias2  = (const float*)d_in[10];
    const float* wc     = (const float*)d_in[11];
    const float* bc     = (const float*)d_in[12];
    float* out = (float*)d_out;

    int E = in_sizes[1] / 2;
    int N = in_sizes[0] / DIN1;
    const int* srcp = ei;
    const int* dstp = ei + E;
    char* ws = (char*)d_ws;

    if (ws_size >= ws_needed(N, 128)) {
        run_pipeline<128, 64>(x, srcp, dstp, et, comp1, basis1, root1, bias1,
                              comp2, basis2, root2, bias2, wc, bc, out, ws, N, E, stream);
    } else if (ws_size >= ws_needed(N, 64)) {
        run_pipeline<64, 64>(x, srcp, dstp, et, comp1, basis1, root1, bias1,
                             comp2, basis2, root2, bias2, wc, bc, out, ws, N, E, stream);
    } else {
        run_pipeline<32, 32>(x, srcp, dstp, et, comp1, basis1, root1, bias1,
                             comp2, basis2, root2, bias2, wc, bc, out, ws, N, E, stream);
    }
}

// Round 3
// 1335.481 us; speedup vs baseline: 2.9253x; 2.9253x over previous
//
#include <hip/hip_runtime.h>

#define R_    16
#define NBAS  30
#define DIN1  128
#define DHID  128
#define DOUT2 64
#define DADR  400

typedef __attribute__((ext_vector_type(8))) short bf16x8;
typedef __attribute__((ext_vector_type(4))) float f32x4;

__device__ __forceinline__ short f2bf(float f) {
    unsigned u = __float_as_uint(f);
    u += 0x7fffu + ((u >> 16) & 1u);   // round-to-nearest-even
    return (short)(u >> 16);
}

// ---------------- count edges per (dst, relation) bucket ----------------
__global__ __launch_bounds__(256) void count_kernel(const int* __restrict__ dst,
                                                    const int* __restrict__ ety,
                                                    float* __restrict__ cnt, int E) {
    int e = blockIdx.x * blockDim.x + threadIdx.x;
    if (e < E) atomicAdd(&cnt[dst[e] * R_ + ety[e]], 1.0f);
}

// ------- wT[o][r*DIN + i] = bf16( sum_b comp[r,b] * basis[b,i,o] ) -------
__global__ __launch_bounds__(256) void weightsT_kernel(const float* __restrict__ comp,
                                                       const float* __restrict__ basis,
                                                       short* __restrict__ wT,
                                                       int DIN, int DOUT, int ldb) {
    int idx = blockIdx.x * blockDim.x + threadIdx.x;
    int total = R_ * DIN * DOUT;
    if (idx >= total) return;
    int o = idx % DOUT;
    int i = (idx / DOUT) % DIN;
    int r = idx / (DOUT * DIN);
    float acc = 0.f;
    #pragma unroll 6
    for (int b = 0; b < NBAS; ++b)
        acc += comp[r * NBAS + b] * basis[((size_t)b * DIN + i) * DOUT + o];
    wT[(size_t)o * ldb + r * DIN + i] = f2bf(acc);
}

// ------- rT[o][i] = bf16(root[i][o]) -------
__global__ __launch_bounds__(256) void transposeT_kernel(const float* __restrict__ root,
                                                         short* __restrict__ rT,
                                                         int DIN, int DOUT) {
    int idx = blockIdx.x * blockDim.x + threadIdx.x;
    if (idx >= DIN * DOUT) return;
    int o = idx % DOUT;
    int i = idx / DOUT;
    rT[(size_t)o * DIN + i] = f2bf(root[(size_t)i * DOUT + o]);
}

// ------- scatter: agg[(dst*R+ety)*64 + j] += feat[src][c0+j], one lane per element -------
__global__ __launch_bounds__(256) void scatter_kernel(const float* __restrict__ feat,
                                                      const int* __restrict__ src,
                                                      const int* __restrict__ dst,
                                                      const int* __restrict__ ety,
                                                      float* __restrict__ agg,
                                                      int E, int featDim, int c0) {
    long long t = (long long)blockIdx.x * 256 + threadIdx.x;
    int e = (int)(t >> 6);
    int j = (int)(t & 63);
    if (e >= E) return;
    int s   = src[e];
    int seg = dst[e] * R_ + ety[e];
    float v = feat[(size_t)s * featDim + c0 + j];
    atomicAdd(&agg[(size_t)seg * 64 + j], v);
}

// ------- MFMA GEMM: H[n][o] (+)= sum_k scale(n,k) * A[n][k] * BT[o][map(k)]
//   scale(n,k) = 1/max(cnt[n*R + (k>>lgCHT)],1) if cnt else 1
//   map(k0)    = (k0>>lgCHT)*DINp + c0 + (k0 & (CHT-1))   (uniform per BK-step)
//   flags&1: init (add bias, no prev read)   flags&2: relu -------
template<int BN, int BK>
__global__ __launch_bounds__(256)
void gemm_kernel(const float* __restrict__ A, int lda,
                 const float* __restrict__ cnt, int lgCHT, int c0, int DINp,
                 const short* __restrict__ BT, int ldb, int Ktot,
                 const float* __restrict__ bias,
                 float* __restrict__ H, int N, int flags)
{
    constexpr int BM  = 64;
    constexpr int WGN = 2;
    constexpr int WGM = 2;
    constexpr int WM  = BM / WGM;          // 32
    constexpr int WN  = BN / WGN;          // 64 or 32
    constexpr int MR  = WM / 16;           // 2
    constexpr int NR  = WN / 16;           // 4 or 2
    constexpr int SWM = BK / 8 - 1;        // swizzle row mask

    __shared__ short lA[BM * BK];
    __shared__ short lB[BN * BK];

    const int tid  = threadIdx.x;
    const int lane = tid & 63;
    const int wv   = tid >> 6;
    const int wr   = wv / WGN;
    const int wcc  = wv % WGN;
    const int nodeBase = blockIdx.x * BM;

    f32x4 acc[MR][NR];
    #pragma unroll
    for (int m = 0; m < MR; ++m)
        #pragma unroll
        for (int n = 0; n < NR; ++n)
            acc[m][n] = (f32x4){0.f, 0.f, 0.f, 0.f};

    for (int k0 = 0; k0 < Ktot; k0 += BK) {
        const int r    = k0 >> lgCHT;
        const int bcol = r * DINp + c0 + (k0 - (r << lgCHT));

        // ---- A tile: BM x BK f32 -> scaled bf16, swizzled ----
        {
            constexpr int C4  = BK / 4;        // float4 per row (16)
            constexpr int RPI = 256 / C4;      // rows per iteration (16)
            const int c4 = tid % C4;
            const int r0 = tid / C4;
            #pragma unroll
            for (int it = 0; it < BM / RPI; ++it) {
                int row  = r0 + it * RPI;
                int grow = nodeBase + row;
                float4 v = {0.f, 0.f, 0.f, 0.f};
                float  s = 1.0f;
                if (grow < N) {
                    v = *(const float4*)(A + (size_t)grow * lda + k0 + c4 * 4);
                    if (cnt) s = 1.0f / fmaxf(cnt[grow * R_ + r], 1.0f);
                }
                short4 b4 = { f2bf(v.x * s), f2bf(v.y * s), f2bf(v.z * s), f2bf(v.w * s) };
                int byte = ((row * BK + c4 * 4) << 1) ^ ((row & SWM) << 4);
                *(short4*)((char*)lA + byte) = b4;
            }
        }
        // ---- B tile: BN x BK bf16, swizzled (BT is [o][Kfull] row-major) ----
        {
            constexpr int C8  = BK / 8;        // 16B units per row (8)
            constexpr int OPI = 256 / C8;      // 32
            const int t8 = tid % C8;
            const int o0 = tid / C8;
            #pragma unroll
            for (int o = o0; o < BN; o += OPI) {
                int4 v = *(const int4*)(BT + (size_t)o * ldb + bcol + t8 * 8);
                int byte = ((o * BK + t8 * 8) << 1) ^ ((o & SWM) << 4);
                *(int4*)((char*)lB + byte) = v;
            }
        }
        __syncthreads();

        #pragma unroll
        for (int kk = 0; kk < BK / 32; ++kk) {
            const int kpos = kk * 32 + (lane >> 4) * 8;
            bf16x8 af[MR], bfr[NR];
            #pragma unroll
            for (int m = 0; m < MR; ++m) {
                int row = wr * WM + m * 16 + (lane & 15);
                af[m] = *(const bf16x8*)((const char*)lA +
                         (((row * BK + kpos) << 1) ^ ((row & SWM) << 4)));
            }
            #pragma unroll
            for (int n = 0; n < NR; ++n) {
                int col = wcc * WN + n * 16 + (lane & 15);
                bfr[n] = *(const bf16x8*)((const char*)lB +
                         (((col * BK + kpos) << 1) ^ ((col & SWM) << 4)));
            }
            #pragma unroll
            for (int m = 0; m < MR; ++m)
                #pragma unroll
                for (int n = 0; n < NR; ++n)
                    acc[m][n] = __builtin_amdgcn_mfma_f32_16x16x32_bf16(
                        af[m], bfr[n], acc[m][n], 0, 0, 0);
        }
        __syncthreads();
    }

    // ---- epilogue: C/D layout row=(lane>>4)*4+i, col=lane&15 ----
    #pragma unroll
    for (int m = 0; m < MR; ++m)
        #pragma unroll
        for (int n = 0; n < NR; ++n)
            #pragma unroll
            for (int i = 0; i < 4; ++i) {
                int row  = wr * WM + m * 16 + ((lane >> 4) << 2) + i;
                int col  = wcc * WN + n * 16 + (lane & 15);
                int grow = nodeBase + row;
                if (grow >= N) continue;
                float v = acc[m][n][i];
                if (flags & 1) v += bias[col];
                else           v += H[(size_t)grow * BN + col];
                if (flags & 2) v = fmaxf(v, 0.f);
                H[(size_t)grow * BN + col] = v;
            }
}

// ------- classifier: out[n][a] = h[n][:] @ wc[:][a] + bc[a], h tile in LDS -------
__global__ __launch_bounds__(256)
void classifier_kernel(const float* __restrict__ h, const float* __restrict__ wc,
                       const float* __restrict__ bc, float* __restrict__ out, int N) {
    constexpr int NB = 32;
    __shared__ float lh[NB * DOUT2];
    const int nb  = blockIdx.x * NB;
    const int tid = threadIdx.x;
    for (int idx = tid; idx < NB * DOUT2; idx += 256) {
        int gn = nb + idx / DOUT2;
        lh[idx] = (gn < N) ? h[(size_t)gn * DOUT2 + (idx % DOUT2)] : 0.f;
    }
    __syncthreads();
    for (int idx = tid; idx < NB * DADR; idx += 256) {
        int nl = idx / DADR, a = idx % DADR;
        int gn = nb + nl;
        if (gn >= N) continue;
        const float* hr = lh + nl * DOUT2;
        float acc = bc[a];
        #pragma unroll 16
        for (int k = 0; k < DOUT2; ++k)
            acc += hr[k] * wc[k * DADR + a];
        out[(size_t)gn * DADR + a] = acc;
    }
}

// ---------------- host-side pipeline (CHT = 64 fixed) ----------------
static void run_pipeline(const float* x, const int* srcp, const int* dstp, const int* et,
                         const float* comp1, const float* basis1, const float* root1, const float* bias1,
                         const float* comp2, const float* basis2, const float* root2, const float* bias2,
                         const float* wc, const float* bc,
                         float* out, char* ws, int N, int E, hipStream_t stream) {
    constexpr int CHT = 64;
    constexpr int lg  = 6;
    const int Kfull = R_ * DIN1;   // 2048

    float* cnt = (float*)ws;                       size_t off = (size_t)N * R_ * 4;
    float* agg = (float*)(ws + off);               off += (size_t)N * R_ * CHT * 4;
    short* w1T = (short*)(ws + off);               off += (size_t)DHID * Kfull * 2;
    short* w2T = (short*)(ws + off);               off += (size_t)DOUT2 * (R_ * DHID) * 2;
    short* r1T = (short*)(ws + off);               off += (size_t)DHID * DIN1 * 2;
    short* r2T = (short*)(ws + off);               off += (size_t)DOUT2 * DHID * 2;
    float* h1  = (float*)(ws + off);               off += (size_t)N * DHID * 4;
    float* h2  = (float*)(ws + off);

    const size_t aggBytes = (size_t)N * R_ * CHT * 4;

    hipMemsetAsync(cnt, 0, (size_t)N * R_ * 4, stream);
    count_kernel<<<(E + 255) / 256, 256, 0, stream>>>(dstp, et, cnt, E);
    weightsT_kernel<<<(R_ * DIN1 * DHID + 255) / 256, 256, 0, stream>>>(comp1, basis1, w1T, DIN1, DHID, Kfull);
    weightsT_kernel<<<(R_ * DHID * DOUT2 + 255) / 256, 256, 0, stream>>>(comp2, basis2, w2T, DHID, DOUT2, R_ * DHID);
    transposeT_kernel<<<(DIN1 * DHID + 255) / 256, 256, 0, stream>>>(root1, r1T, DIN1, DHID);
    transposeT_kernel<<<(DHID * DOUT2 + 255) / 256, 256, 0, stream>>>(root2, r2T, DHID, DOUT2);

    const int gGrid = (N + 63) / 64;
    const long long sthreads = (long long)E * 64;
    const int sGrid = (int)((sthreads + 255) / 256);
    constexpr int NC = DIN1 / CHT;   // 2 chunks (DIN1 == DHID)

    // ---- layer 1: x -> h1 (relu) ----
    gemm_kernel<DHID, 64><<<gGrid, 256, 0, stream>>>(x, DIN1, nullptr, 7, 0, DIN1,
                                                     r1T, DIN1, DIN1, bias1, h1, N, 1);
    for (int c = 0; c < NC; ++c) {
        hipMemsetAsync(agg, 0, aggBytes, stream);
        scatter_kernel<<<sGrid, 256, 0, stream>>>(x, srcp, dstp, et, agg, E, DIN1, c * CHT);
        int flags = (c == NC - 1) ? 2 : 0;
        gemm_kernel<DHID, 64><<<gGrid, 256, 0, stream>>>(agg, R_ * CHT, cnt, lg, c * CHT, DIN1,
                                                         w1T, Kfull, R_ * CHT, bias1, h1, N, flags);
    }

    // ---- layer 2: h1 -> h2 ----
    gemm_kernel<DOUT2, 64><<<gGrid, 256, 0, stream>>>(h1, DHID, nullptr, 7, 0, DHID,
                                                      r2T, DHID, DHID, bias2, h2, N, 1);
    for (int c = 0; c < NC; ++c) {
        hipMemsetAsync(agg, 0, aggBytes, stream);
        scatter_kernel<<<sGrid, 256, 0, stream>>>(h1, srcp, dstp, et, agg, E, DHID, c * CHT);
        gemm_kernel<DOUT2, 64><<<gGrid, 256, 0, stream>>>(agg, R_ * CHT, cnt, lg, c * CHT, DHID,
                                                          w2T, R_ * DHID, R_ * CHT, bias2, h2, N, 0);
    }

    // ---- classifier ----
    classifier_kernel<<<(N + 31) / 32, 256, 0, stream>>>(h2, wc, bc, out, N);
}

extern "C" void kernel_launch(void* const* d_in, const int* in_sizes, int n_in,
                              void* d_out, int out_size, void* d_ws, size_t ws_size,
                              hipStream_t stream) {
    const float* x      = (const float*)d_in[0];
    const int*   ei     = (const int*)d_in[1];
    const int*   et     = (const int*)d_in[2];
    const float* comp1  = (const float*)d_in[3];
    const float* basis1 = (const float*)d_in[4];
    const float* root1  = (const float*)d_in[5];
    const float* bias1  = (const float*)d_in[6];
    const float* comp2  = (const float*)d_in[7];
    const float* basis2 = (const float*)d_in[8];
    const float* root2  = (const float*)d_in[9];
    const float* bias2  = (const float*)d_in[10];
    const float* wc     = (const float*)d_in[11];
    const float* bc     = (const float*)d_in[12];
    float* out = (float*)d_out;

    int E = in_sizes[1] / 2;
    int N = in_sizes[0] / DIN1;
    const int* srcp = ei;
    const int* dstp = ei + E;
    char* ws = (char*)d_ws;

    run_pipeline(x, srcp, dstp, et, comp1, basis1, root1, bias1,
                 comp2, basis2, root2, bias2, wc, bc, out, ws, N, E, stream);
}

// Round 4
// 850.978 us; speedup vs baseline: 4.5908x; 1.5693x over previous
//
#include <hip/hip_runtime.h>

#define R_    16
#define NBAS  30
#define DIN1  128
#define DHID  128
#define DOUT2 64
#define DADR  400
#define KCH   128              // feature width of both layer inputs
#define LDB   ((R_ + 1) * 128) // combined weight row length (16 relations + root)

typedef __attribute__((ext_vector_type(8))) short bf16x8;
typedef __attribute__((ext_vector_type(4))) float f32x4;

__device__ __forceinline__ short f2bf(float f) {
    unsigned u = __float_as_uint(f);
    u += 0x7fffu + ((u >> 16) & 1u);   // round-to-nearest-even
    return (short)(u >> 16);
}

// ---------------- int counts per (dst, relation) segment ----------------
__global__ __launch_bounds__(256) void count_kernel(const int* __restrict__ dst,
                                                    const int* __restrict__ ety,
                                                    int* __restrict__ cnt, int E) {
    int e = blockIdx.x * blockDim.x + threadIdx.x;
    if (e < E) atomicAdd(&cnt[dst[e] * R_ + ety[e]], 1);
}

// ---------------- 3-phase exclusive scan over nseg counts ----------------
#define SCAN_CHUNK 2048
#define SCAN_IT    8

__global__ __launch_bounds__(256) void scan_bsum_kernel(const int* __restrict__ cnt, int nseg,
                                                        int* __restrict__ bsum) {
    __shared__ int sd[256];
    int base = blockIdx.x * SCAN_CHUNK;
    int s = 0;
    #pragma unroll
    for (int j = 0; j < SCAN_IT; ++j) {
        int idx = base + j * 256 + threadIdx.x;
        if (idx < nseg) s += cnt[idx];
    }
    sd[threadIdx.x] = s;
    __syncthreads();
    for (int st = 128; st > 0; st >>= 1) {
        if (threadIdx.x < st) sd[threadIdx.x] += sd[threadIdx.x + st];
        __syncthreads();
    }
    if (threadIdx.x == 0) bsum[blockIdx.x] = sd[0];
}

__global__ __launch_bounds__(256) void scan_top_kernel(const int* __restrict__ bsum, int nblk,
                                                       int* __restrict__ boff,
                                                       int* __restrict__ off, int nseg) {
    if (nblk > 256) {                       // safety fallback (not expected)
        if (threadIdx.x == 0) {
            int run = 0;
            for (int i = 0; i < nblk; ++i) { int t = bsum[i]; boff[i] = run; run += t; }
            off[nseg] = run;
        }
        return;
    }
    __shared__ int sd[256];
    int v = (threadIdx.x < nblk) ? bsum[threadIdx.x] : 0;
    sd[threadIdx.x] = v;
    __syncthreads();
    for (int st = 1; st < 256; st <<= 1) {
        int t = (threadIdx.x >= st) ? sd[threadIdx.x - st] : 0;
        __syncthreads();
        sd[threadIdx.x] += t;
        __syncthreads();
    }
    if (threadIdx.x < nblk) boff[threadIdx.x] = sd[threadIdx.x] - v;   // exclusive
    if (threadIdx.x == nblk - 1) off[nseg] = sd[threadIdx.x];          // total = E
}

__global__ __launch_bounds__(256) void scan_final_kernel(const int* __restrict__ cnt, int nseg,
                                                         const int* __restrict__ boff,
                                                         int* __restrict__ off) {
    __shared__ int sd[256];
    int base = blockIdx.x * SCAN_CHUNK + threadIdx.x * SCAN_IT;
    int v[SCAN_IT];
    int s = 0;
    #pragma unroll
    for (int j = 0; j < SCAN_IT; ++j) {
        int idx = base + j;
        v[j] = (idx < nseg) ? cnt[idx] : 0;
        s += v[j];
    }
    sd[threadIdx.x] = s;
    __syncthreads();
    for (int st = 1; st < 256; st <<= 1) {
        int t = (threadIdx.x >= st) ? sd[threadIdx.x - st] : 0;
        __syncthreads();
        sd[threadIdx.x] += t;
        __syncthreads();
    }
    int run = boff[blockIdx.x] + sd[threadIdx.x] - s;   // exclusive prefix of this thread
    #pragma unroll
    for (int j = 0; j < SCAN_IT; ++j) {
        int idx = base + j;
        if (idx < nseg) off[idx] = run;
        run += v[j];
    }
}

// ---------------- bucket the source indices (CSR payload) ----------------
__global__ __launch_bounds__(256) void reorder_kernel(const int* __restrict__ src,
                                                      const int* __restrict__ dst,
                                                      const int* __restrict__ ety,
                                                      int* __restrict__ cursor,
                                                      int* __restrict__ srt, int E) {
    int e = blockIdx.x * blockDim.x + threadIdx.x;
    if (e >= E) return;
    int seg = dst[e] * R_ + ety[e];
    int pos = atomicAdd(&cursor[seg], 1);
    srt[pos] = src[e];
}

// ------- BT[o][r*DIN + i] = bf16( sum_b comp[r,b] * basis[b,i,o] ), ldb = LDB -------
__global__ __launch_bounds__(256) void weightsT_kernel(const float* __restrict__ comp,
                                                       const float* __restrict__ basis,
                                                       short* __restrict__ wT,
                                                       int DIN, int DOUT) {
    int idx = blockIdx.x * blockDim.x + threadIdx.x;
    int total = R_ * DIN * DOUT;
    if (idx >= total) return;
    int o = idx % DOUT;
    int i = (idx / DOUT) % DIN;
    int r = idx / (DOUT * DIN);
    float acc = 0.f;
    #pragma unroll 6
    for (int b = 0; b < NBAS; ++b)
        acc += comp[r * NBAS + b] * basis[((size_t)b * DIN + i) * DOUT + o];
    wT[(size_t)o * LDB + r * DIN + i] = f2bf(acc);
}

// ------- BT[o][R_*DIN + i] = bf16(root[i][o]) -------
__global__ __launch_bounds__(256) void rootT_kernel(const float* __restrict__ root,
                                                    short* __restrict__ wT,
                                                    int DIN, int DOUT) {
    int idx = blockIdx.x * blockDim.x + threadIdx.x;
    if (idx >= DIN * DOUT) return;
    int o = idx % DOUT;
    int i = idx / DOUT;
    wT[(size_t)o * LDB + R_ * DIN + i] = f2bf(root[(size_t)i * DOUT + o]);
}

// ------- fused CSR-aggregate + MFMA GEMM:
//   H[n][o] = relu?( sum_r (1/cnt) sum_i mean_agg[n,r,i] * W_r[i,o]  +  x[n]@root + bias ) -------
template<int BN>
__global__ __launch_bounds__(256)
void rgcn_gemm_kernel(const float* __restrict__ feat,     // gather source AND root input, [N][128]
                      const int* __restrict__ off,
                      const int* __restrict__ srt,
                      const short* __restrict__ BT,       // [BN][LDB] bf16
                      const float* __restrict__ bias,
                      float* __restrict__ H, int N, int relu)
{
    constexpr int BM = 64, BK = 128;
    constexpr int WGN = 2, WGM = 2;
    constexpr int WM = BM / WGM;     // 32
    constexpr int WN = BN / WGN;     // 64 (BN=128) or 32 (BN=64)
    constexpr int MR = WM / 16;      // 2
    constexpr int NR = WN / 16;      // 4 or 2

    __shared__ short lA[BM * BK];
    __shared__ short lB[BN * BK];

    const int tid  = threadIdx.x;
    const int lane = tid & 63;
    const int wv   = tid >> 6;
    const int wr   = wv / WGN;
    const int wcc  = wv % WGN;
    const int nodeBase = blockIdx.x * BM;

    f32x4 acc[MR][NR];
    #pragma unroll
    for (int m = 0; m < MR; ++m)
        #pragma unroll
        for (int n = 0; n < NR; ++n)
            acc[m][n] = (f32x4){0.f, 0.f, 0.f, 0.f};

    const int c4 = tid & 31;     // float4 slot within 128-wide row
    const int r0 = tid >> 5;     // 8 rows per pass

    for (int r = 0; r <= R_; ++r) {
        const int k0 = r * BK;

        // ---- A tile: 64 x 128, aggregated from CSR (r<R_) or dense root input ----
        if (r < R_) {
            #pragma unroll
            for (int it = 0; it < 8; ++it) {
                int row  = it * 8 + r0;
                int grow = nodeBase + row;
                float4 a = {0.f, 0.f, 0.f, 0.f};
                float  s = 1.f;
                if (grow < N) {
                    int seg = grow * R_ + r;
                    int beg = off[seg], end = off[seg + 1];
                    for (int p = beg; p < end; ++p) {
                        const float4* xr = (const float4*)(feat + (size_t)srt[p] * KCH);
                        float4 v = xr[c4];
                        a.x += v.x; a.y += v.y; a.z += v.z; a.w += v.w;
                    }
                    int c = end - beg;
                    s = 1.f / (float)(c > 1 ? c : 1);
                }
                short4 b4 = { f2bf(a.x * s), f2bf(a.y * s), f2bf(a.z * s), f2bf(a.w * s) };
                int byte = ((row * BK + c4 * 4) << 1) ^ ((row & 15) << 4);
                *(short4*)((char*)lA + byte) = b4;
            }
        } else {
            #pragma unroll
            for (int it = 0; it < 8; ++it) {
                int row  = it * 8 + r0;
                int grow = nodeBase + row;
                float4 a = {0.f, 0.f, 0.f, 0.f};
                if (grow < N) a = ((const float4*)(feat + (size_t)grow * KCH))[c4];
                short4 b4 = { f2bf(a.x), f2bf(a.y), f2bf(a.z), f2bf(a.w) };
                int byte = ((row * BK + c4 * 4) << 1) ^ ((row & 15) << 4);
                *(short4*)((char*)lA + byte) = b4;
            }
        }

        // ---- B tile: BN x 128 bf16 from combined BT ----
        {
            const int t8 = tid & 15;     // 16B unit within row
            const int o0 = tid >> 4;     // 16 rows per pass
            #pragma unroll
            for (int o = o0; o < BN; o += 16) {
                int4 v = *(const int4*)(BT + (size_t)o * LDB + k0 + t8 * 8);
                int byte = ((o * BK + t8 * 8) << 1) ^ ((o & 15) << 4);
                *(int4*)((char*)lB + byte) = v;
            }
        }
        __syncthreads();

        #pragma unroll
        for (int kk = 0; kk < BK / 32; ++kk) {
            const int kpos = kk * 32 + (lane >> 4) * 8;
            bf16x8 af[MR], bfr[NR];
            #pragma unroll
            for (int m = 0; m < MR; ++m) {
                int row = wr * WM + m * 16 + (lane & 15);
                af[m] = *(const bf16x8*)((const char*)lA +
                         (((row * BK + kpos) << 1) ^ ((row & 15) << 4)));
            }
            #pragma unroll
            for (int n = 0; n < NR; ++n) {
                int col = wcc * WN + n * 16 + (lane & 15);
                bfr[n] = *(const bf16x8*)((const char*)lB +
                         (((col * BK + kpos) << 1) ^ ((col & 15) << 4)));
            }
            #pragma unroll
            for (int m = 0; m < MR; ++m)
                #pragma unroll
                for (int n = 0; n < NR; ++n)
                    acc[m][n] = __builtin_amdgcn_mfma_f32_16x16x32_bf16(
                        af[m], bfr[n], acc[m][n], 0, 0, 0);
        }
        __syncthreads();
    }

    // ---- epilogue: C/D layout row=(lane>>4)*4+i, col=lane&15 ----
    #pragma unroll
    for (int m = 0; m < MR; ++m)
        #pragma unroll
        for (int n = 0; n < NR; ++n)
            #pragma unroll
            for (int i = 0; i < 4; ++i) {
                int row  = wr * WM + m * 16 + ((lane >> 4) << 2) + i;
                int col  = wcc * WN + n * 16 + (lane & 15);
                int grow = nodeBase + row;
                if (grow >= N) continue;
                float v = acc[m][n][i] + bias[col];
                if (relu) v = fmaxf(v, 0.f);
                H[(size_t)grow * BN + col] = v;
            }
}

// ------- classifier: out[n][a] = h[n][:] @ wc[:][a] + bc[a], h tile in LDS -------
__global__ __launch_bounds__(256)
void classifier_kernel(const float* __restrict__ h, const float* __restrict__ wc,
                       const float* __restrict__ bc, float* __restrict__ out, int N) {
    constexpr int NB = 32;
    __shared__ float lh[NB * DOUT2];
    const int nb  = blockIdx.x * NB;
    const int tid = threadIdx.x;
    for (int idx = tid; idx < NB * DOUT2; idx += 256) {
        int gn = nb + idx / DOUT2;
        lh[idx] = (gn < N) ? h[(size_t)gn * DOUT2 + (idx % DOUT2)] : 0.f;
    }
    __syncthreads();
    for (int idx = tid; idx < NB * DADR; idx += 256) {
        int nl = idx / DADR, a = idx % DADR;
        int gn = nb + nl;
        if (gn >= N) continue;
        const float* hr = lh + nl * DOUT2;
        float acc = bc[a];
        #pragma unroll 16
        for (int k = 0; k < DOUT2; ++k)
            acc += hr[k] * wc[k * DADR + a];
        out[(size_t)gn * DADR + a] = acc;
    }
}

static inline size_t align16(size_t x) { return (x + 15) & ~(size_t)15; }

extern "C" void kernel_launch(void* const* d_in, const int* in_sizes, int n_in,
                              void* d_out, int out_size, void* d_ws, size_t ws_size,
                              hipStream_t stream) {
    const float* x      = (const float*)d_in[0];
    const int*   ei     = (const int*)d_in[1];
    const int*   et     = (const int*)d_in[2];
    const float* comp1  = (const float*)d_in[3];
    const float* basis1 = (const float*)d_in[4];
    const float* root1  = (const float*)d_in[5];
    const float* bias1  = (const float*)d_in[6];
    const float* comp2  = (const float*)d_in[7];
    const float* basis2 = (const float*)d_in[8];
    const float* root2  = (const float*)d_in[9];
    const float* bias2  = (const float*)d_in[10];
    const float* wc     = (const float*)d_in[11];
    const float* bc     = (const float*)d_in[12];
    float* out = (float*)d_out;

    const int E = in_sizes[1] / 2;
    const int N = in_sizes[0] / DIN1;
    const int* srcp = ei;
    const int* dstp = ei + E;

    const int NSEG = N * R_;
    const int NBLK = (NSEG + SCAN_CHUNK - 1) / SCAN_CHUNK;

    char* ws = (char*)d_ws;
    size_t o = 0;
    int*   cntI   = (int*)(ws + o);  o = align16(o + (size_t)NSEG * 4);
    int*   off    = (int*)(ws + o);  o = align16(o + (size_t)(NSEG + 1) * 4);
    int*   cursor = (int*)(ws + o);  o = align16(o + (size_t)NSEG * 4);
    int*   bsum   = (int*)(ws + o);  o = align16(o + (size_t)NBLK * 4);
    int*   boff   = (int*)(ws + o);  o = align16(o + (size_t)NBLK * 4);
    int*   srt    = (int*)(ws + o);  o = align16(o + (size_t)E * 4);
    short* BT1    = (short*)(ws + o); o = align16(o + (size_t)DHID * LDB * 2);
    short* BT2    = (short*)(ws + o); o = align16(o + (size_t)DOUT2 * LDB * 2);
    float* h1     = (float*)(ws + o); o = align16(o + (size_t)N * DHID * 4);
    float* h2     = (float*)(ws + o);

    // ---- CSR build ----
    hipMemsetAsync(cntI, 0, (size_t)NSEG * 4, stream);
    count_kernel<<<(E + 255) / 256, 256, 0, stream>>>(dstp, et, cntI, E);
    scan_bsum_kernel<<<NBLK, 256, 0, stream>>>(cntI, NSEG, bsum);
    scan_top_kernel<<<1, 256, 0, stream>>>(bsum, NBLK, boff, off, NSEG);
    scan_final_kernel<<<NBLK, 256, 0, stream>>>(cntI, NSEG, boff, off);
    hipMemcpyAsync(cursor, off, (size_t)NSEG * 4, hipMemcpyDeviceToDevice, stream);
    reorder_kernel<<<(E + 255) / 256, 256, 0, stream>>>(srcp, dstp, et, cursor, srt, E);

    // ---- weights (combined per-layer BT: 16 relations + root) ----
    weightsT_kernel<<<(R_ * DIN1 * DHID + 255) / 256, 256, 0, stream>>>(comp1, basis1, BT1, DIN1, DHID);
    weightsT_kernel<<<(R_ * DHID * DOUT2 + 255) / 256, 256, 0, stream>>>(comp2, basis2, BT2, DHID, DOUT2);
    rootT_kernel<<<(DIN1 * DHID + 255) / 256, 256, 0, stream>>>(root1, BT1, DIN1, DHID);
    rootT_kernel<<<(DHID * DOUT2 + 255) / 256, 256, 0, stream>>>(root2, BT2, DHID, DOUT2);

    // ---- two fused RGCN layers + classifier ----
    const int gGrid = (N + 63) / 64;
    rgcn_gemm_kernel<DHID><<<gGrid, 256, 0, stream>>>(x,  off, srt, BT1, bias1, h1, N, 1);
    rgcn_gemm_kernel<DOUT2><<<gGrid, 256, 0, stream>>>(h1, off, srt, BT2, bias2, h2, N, 0);
    classifier_kernel<<<(N + 31) / 32, 256, 0, stream>>>(h2, wc, bc, out, N);
}

// Round 5
// 616.408 us; speedup vs baseline: 6.3378x; 1.3805x over previous
//
#include <hip/hip_runtime.h>

#define R_    16
#define NBAS  30
#define DIN1  128
#define DHID  128
#define DOUT2 64
#define DADR  400
#define KCH   128              // feature width of both layer inputs
#define LDB   ((R_ + 1) * 128) // combined weight row length (16 relations + root)

typedef __attribute__((ext_vector_type(8))) short bf16x8;
typedef __attribute__((ext_vector_type(4))) float f32x4;

__device__ __forceinline__ short f2bf(float f) {
    unsigned u = __float_as_uint(f);
    u += 0x7fffu + ((u >> 16) & 1u);   // round-to-nearest-even
    return (short)(u >> 16);
}
__device__ __forceinline__ float bf2f(short s) {
    return __uint_as_float(((unsigned)(unsigned short)s) << 16);
}

// ---------------- f32 -> bf16 bulk convert (float4 -> short4 per thread) ----------------
__global__ __launch_bounds__(256) void tobf_kernel(const float* __restrict__ in,
                                                   short* __restrict__ out, int n4) {
    int i = blockIdx.x * 256 + threadIdx.x;
    if (i >= n4) return;
    float4 v = ((const float4*)in)[i];
    short4 b = { f2bf(v.x), f2bf(v.y), f2bf(v.z), f2bf(v.w) };
    ((short4*)out)[i] = b;
}

// ---------------- int counts per (dst, relation) segment ----------------
__global__ __launch_bounds__(256) void count_kernel(const int* __restrict__ dst,
                                                    const int* __restrict__ ety,
                                                    int* __restrict__ cnt, int E) {
    int e = blockIdx.x * blockDim.x + threadIdx.x;
    if (e < E) atomicAdd(&cnt[dst[e] * R_ + ety[e]], 1);
}

// ---------------- 3-phase exclusive scan over nseg counts ----------------
#define SCAN_CHUNK 2048
#define SCAN_IT    8

__global__ __launch_bounds__(256) void scan_bsum_kernel(const int* __restrict__ cnt, int nseg,
                                                        int* __restrict__ bsum) {
    __shared__ int sd[256];
    int base = blockIdx.x * SCAN_CHUNK;
    int s = 0;
    #pragma unroll
    for (int j = 0; j < SCAN_IT; ++j) {
        int idx = base + j * 256 + threadIdx.x;
        if (idx < nseg) s += cnt[idx];
    }
    sd[threadIdx.x] = s;
    __syncthreads();
    for (int st = 128; st > 0; st >>= 1) {
        if (threadIdx.x < st) sd[threadIdx.x] += sd[threadIdx.x + st];
        __syncthreads();
    }
    if (threadIdx.x == 0) bsum[blockIdx.x] = sd[0];
}

__global__ __launch_bounds__(256) void scan_top_kernel(const int* __restrict__ bsum, int nblk,
                                                       int* __restrict__ boff,
                                                       int* __restrict__ off, int nseg) {
    if (nblk > 256) {
        if (threadIdx.x == 0) {
            int run = 0;
            for (int i = 0; i < nblk; ++i) { int t = bsum[i]; boff[i] = run; run += t; }
            off[nseg] = run;
        }
        return;
    }
    __shared__ int sd[256];
    int v = (threadIdx.x < nblk) ? bsum[threadIdx.x] : 0;
    sd[threadIdx.x] = v;
    __syncthreads();
    for (int st = 1; st < 256; st <<= 1) {
        int t = (threadIdx.x >= st) ? sd[threadIdx.x - st] : 0;
        __syncthreads();
        sd[threadIdx.x] += t;
        __syncthreads();
    }
    if (threadIdx.x < nblk) boff[threadIdx.x] = sd[threadIdx.x] - v;   // exclusive
    if (threadIdx.x == nblk - 1) off[nseg] = sd[threadIdx.x];          // total = E
}

__global__ __launch_bounds__(256) void scan_final_kernel(const int* __restrict__ cnt, int nseg,
                                                         const int* __restrict__ boff,
                                                         int* __restrict__ off) {
    __shared__ int sd[256];
    int base = blockIdx.x * SCAN_CHUNK + threadIdx.x * SCAN_IT;
    int v[SCAN_IT];
    int s = 0;
    #pragma unroll
    for (int j = 0; j < SCAN_IT; ++j) {
        int idx = base + j;
        v[j] = (idx < nseg) ? cnt[idx] : 0;
        s += v[j];
    }
    sd[threadIdx.x] = s;
    __syncthreads();
    for (int st = 1; st < 256; st <<= 1) {
        int t = (threadIdx.x >= st) ? sd[threadIdx.x - st] : 0;
        __syncthreads();
        sd[threadIdx.x] += t;
        __syncthreads();
    }
    int run = boff[blockIdx.x] + sd[threadIdx.x] - s;   // exclusive prefix of this thread
    #pragma unroll
    for (int j = 0; j < SCAN_IT; ++j) {
        int idx = base + j;
        if (idx < nseg) off[idx] = run;
        run += v[j];
    }
}

// ---------------- bucket the source indices (CSR payload) ----------------
__global__ __launch_bounds__(256) void reorder_kernel(const int* __restrict__ src,
                                                      const int* __restrict__ dst,
                                                      const int* __restrict__ ety,
                                                      int* __restrict__ cursor,
                                                      int* __restrict__ srt, int E) {
    int e = blockIdx.x * blockDim.x + threadIdx.x;
    if (e >= E) return;
    int seg = dst[e] * R_ + ety[e];
    int pos = atomicAdd(&cursor[seg], 1);
    srt[pos] = src[e];
}

// ------- BT[o][r*DIN + i] = bf16( sum_b comp[r,b] * basis[b,i,o] ), ldb = LDB -------
__global__ __launch_bounds__(256) void weightsT_kernel(const float* __restrict__ comp,
                                                       const float* __restrict__ basis,
                                                       short* __restrict__ wT,
                                                       int DIN, int DOUT) {
    int idx = blockIdx.x * blockDim.x + threadIdx.x;
    int total = R_ * DIN * DOUT;
    if (idx >= total) return;
    int o = idx % DOUT;
    int i = (idx / DOUT) % DIN;
    int r = idx / (DOUT * DIN);
    float acc = 0.f;
    #pragma unroll 6
    for (int b = 0; b < NBAS; ++b)
        acc += comp[r * NBAS + b] * basis[((size_t)b * DIN + i) * DOUT + o];
    wT[(size_t)o * LDB + r * DIN + i] = f2bf(acc);
}

// ------- BT[o][R_*DIN + i] = bf16(root[i][o]) -------
__global__ __launch_bounds__(256) void rootT_kernel(const float* __restrict__ root,
                                                    short* __restrict__ wT,
                                                    int DIN, int DOUT) {
    int idx = blockIdx.x * blockDim.x + threadIdx.x;
    if (idx >= DIN * DOUT) return;
    int o = idx % DOUT;
    int i = idx / DOUT;
    wT[(size_t)o * LDB + R_ * DIN + i] = f2bf(root[(size_t)i * DOUT + o]);
}

// ------- fused CSR-aggregate + MFMA GEMM (bf16 gather source):
//   H[n][o] = relu?( sum_r (1/cnt) sum_i mean_agg[n,r,i] * W_r[i,o]  +  x[n]@root + bias ) -------
template<int BN, bool OUTBF>
__global__ __launch_bounds__(256)
void rgcn_gemm_kernel(const short* __restrict__ featbf,   // [N][128] bf16: gather + root input
                      const int* __restrict__ off,
                      const int* __restrict__ srt,
                      const short* __restrict__ BT,       // [BN][LDB] bf16
                      const float* __restrict__ bias,
                      void* __restrict__ Hout, int N, int relu)
{
    constexpr int BM = 32, BK = 128;
    constexpr int WN = BN / 4;       // 32 (BN=128) or 16 (BN=64)
    constexpr int MR = 2;            // 32 rows / 16
    constexpr int NR = WN / 16;      // 2 or 1

    __shared__ short lA[BM * BK];
    __shared__ short lB[BN * BK];

    const int tid  = threadIdx.x;
    const int lane = tid & 63;
    const int wv   = tid >> 6;       // wave = N-column group
    const int nodeBase = blockIdx.x * BM;

    f32x4 acc[MR][NR];
    #pragma unroll
    for (int m = 0; m < MR; ++m)
        #pragma unroll
        for (int n = 0; n < NR; ++n)
            acc[m][n] = (f32x4){0.f, 0.f, 0.f, 0.f};

    const int c4 = tid & 31;     // short4 slot within 128-wide row (4 bf16 = 8B)
    const int r0 = tid >> 5;     // 8 rows per pass

    for (int r = 0; r <= R_; ++r) {
        const int k0 = r * BK;

        // ---- A tile: 32 x 128 bf16, aggregated from CSR (r<R_) or dense root copy ----
        if (r < R_) {
            #pragma unroll
            for (int it = 0; it < 4; ++it) {
                int row  = it * 8 + r0;
                int grow = nodeBase + row;
                float a0 = 0.f, a1 = 0.f, a2 = 0.f, a3 = 0.f;
                float s = 1.f;
                if (grow < N) {
                    int seg = grow * R_ + r;
                    int beg = off[seg], end = off[seg + 1];
                    for (int p = beg; p < end; ++p) {
                        short4 v = ((const short4*)(featbf + (size_t)srt[p] * KCH))[c4];
                        a0 += bf2f(v.x); a1 += bf2f(v.y);
                        a2 += bf2f(v.z); a3 += bf2f(v.w);
                    }
                    int c = end - beg;
                    s = 1.f / (float)(c > 1 ? c : 1);
                }
                short4 b4 = { f2bf(a0 * s), f2bf(a1 * s), f2bf(a2 * s), f2bf(a3 * s) };
                int byte = ((row * BK + c4 * 4) << 1) ^ ((row & 15) << 4);
                *(short4*)((char*)lA + byte) = b4;
            }
        } else {
            #pragma unroll
            for (int it = 0; it < 4; ++it) {
                int row  = it * 8 + r0;
                int grow = nodeBase + row;
                short4 v = {0, 0, 0, 0};
                if (grow < N) v = ((const short4*)(featbf + (size_t)grow * KCH))[c4];
                int byte = ((row * BK + c4 * 4) << 1) ^ ((row & 15) << 4);
                *(short4*)((char*)lA + byte) = v;
            }
        }

        // ---- B tile: BN x 128 bf16 from combined BT ----
        {
            const int t8 = tid & 15;     // 16B unit within row
            const int o0 = tid >> 4;     // 16 rows per pass
            #pragma unroll
            for (int o = o0; o < BN; o += 16) {
                int4 v = *(const int4*)(BT + (size_t)o * LDB + k0 + t8 * 8);
                int byte = ((o * BK + t8 * 8) << 1) ^ ((o & 15) << 4);
                *(int4*)((char*)lB + byte) = v;
            }
        }
        __syncthreads();

        #pragma unroll
        for (int kk = 0; kk < BK / 32; ++kk) {
            const int kpos = kk * 32 + (lane >> 4) * 8;
            bf16x8 af[MR], bfr[NR];
            #pragma unroll
            for (int m = 0; m < MR; ++m) {
                int row = m * 16 + (lane & 15);
                af[m] = *(const bf16x8*)((const char*)lA +
                         (((row * BK + kpos) << 1) ^ ((row & 15) << 4)));
            }
            #pragma unroll
            for (int n = 0; n < NR; ++n) {
                int col = wv * WN + n * 16 + (lane & 15);
                bfr[n] = *(const bf16x8*)((const char*)lB +
                         (((col * BK + kpos) << 1) ^ ((col & 15) << 4)));
            }
            #pragma unroll
            for (int m = 0; m < MR; ++m)
                #pragma unroll
                for (int n = 0; n < NR; ++n)
                    acc[m][n] = __builtin_amdgcn_mfma_f32_16x16x32_bf16(
                        af[m], bfr[n], acc[m][n], 0, 0, 0);
        }
        __syncthreads();
    }

    // ---- epilogue: C/D layout row=(lane>>4)*4+i, col=lane&15 ----
    #pragma unroll
    for (int m = 0; m < MR; ++m)
        #pragma unroll
        for (int n = 0; n < NR; ++n)
            #pragma unroll
            for (int i = 0; i < 4; ++i) {
                int row  = m * 16 + ((lane >> 4) << 2) + i;
                int col  = wv * WN + n * 16 + (lane & 15);
                int grow = nodeBase + row;
                if (grow >= N) continue;
                float v = acc[m][n][i] + bias[col];
                if (relu) v = fmaxf(v, 0.f);
                if (OUTBF) ((short*)Hout)[(size_t)grow * BN + col] = f2bf(v);
                else       ((float*)Hout)[(size_t)grow * BN + col] = v;
            }
}

// ------- classifier: out[n][a] = h[n][:] @ wc[:][a] + bc[a], h tile in LDS -------
__global__ __launch_bounds__(256)
void classifier_kernel(const float* __restrict__ h, const float* __restrict__ wc,
                       const float* __restrict__ bc, float* __restrict__ out, int N) {
    constexpr int NB = 32;
    __shared__ float lh[NB * DOUT2];
    const int nb  = blockIdx.x * NB;
    const int tid = threadIdx.x;
    for (int idx = tid; idx < NB * DOUT2; idx += 256) {
        int gn = nb + idx / DOUT2;
        lh[idx] = (gn < N) ? h[(size_t)gn * DOUT2 + (idx % DOUT2)] : 0.f;
    }
    __syncthreads();
    for (int idx = tid; idx < NB * DADR; idx += 256) {
        int nl = idx / DADR, a = idx % DADR;
        int gn = nb + nl;
        if (gn >= N) continue;
        const float* hr = lh + nl * DOUT2;
        float acc = bc[a];
        #pragma unroll 16
        for (int k = 0; k < DOUT2; ++k)
            acc += hr[k] * wc[k * DADR + a];
        out[(size_t)gn * DADR + a] = acc;
    }
}

static inline size_t align16(size_t x) { return (x + 15) & ~(size_t)15; }

extern "C" void kernel_launch(void* const* d_in, const int* in_sizes, int n_in,
                              void* d_out, int out_size, void* d_ws, size_t ws_size,
                              hipStream_t stream) {
    const float* x      = (const float*)d_in[0];
    const int*   ei     = (const int*)d_in[1];
    const int*   et     = (const int*)d_in[2];
    const float* comp1  = (const float*)d_in[3];
    const float* basis1 = (const float*)d_in[4];
    const float* root1  = (const float*)d_in[5];
    const float* bias1  = (const float*)d_in[6];
    const float* comp2  = (const float*)d_in[7];
    const float* basis2 = (const float*)d_in[8];
    const float* root2  = (const float*)d_in[9];
    const float* bias2  = (const float*)d_in[10];
    const float* wc     = (const float*)d_in[11];
    const float* bc     = (const float*)d_in[12];
    float* out = (float*)d_out;

    const int E = in_sizes[1] / 2;
    const int N = in_sizes[0] / DIN1;
    const int* srcp = ei;
    const int* dstp = ei + E;

    const int NSEG = N * R_;
    const int NBLK = (NSEG + SCAN_CHUNK - 1) / SCAN_CHUNK;

    char* ws = (char*)d_ws;
    size_t o = 0;
    int*   cntI   = (int*)(ws + o);   o = align16(o + (size_t)NSEG * 4);
    int*   off    = (int*)(ws + o);   o = align16(o + (size_t)(NSEG + 1) * 4);
    int*   cursor = (int*)(ws + o);   o = align16(o + (size_t)NSEG * 4);
    int*   bsum   = (int*)(ws + o);   o = align16(o + (size_t)NBLK * 4);
    int*   boff   = (int*)(ws + o);   o = align16(o + (size_t)NBLK * 4);
    int*   srt    = (int*)(ws + o);   o = align16(o + (size_t)E * 4);
    short* BT1    = (short*)(ws + o); o = align16(o + (size_t)DHID * LDB * 2);
    short* BT2    = (short*)(ws + o); o = align16(o + (size_t)DOUT2 * LDB * 2);
    short* xbf    = (short*)(ws + o); o = align16(o + (size_t)N * DIN1 * 2);
    short* h1bf   = (short*)(ws + o); o = align16(o + (size_t)N * DHID * 2);
    float* h2     = (float*)(ws + o);

    // ---- bf16 copy of x ----
    const int n4 = N * DIN1 / 4;
    tobf_kernel<<<(n4 + 255) / 256, 256, 0, stream>>>(x, xbf, n4);

    // ---- CSR build ----
    hipMemsetAsync(cntI, 0, (size_t)NSEG * 4, stream);
    count_kernel<<<(E + 255) / 256, 256, 0, stream>>>(dstp, et, cntI, E);
    scan_bsum_kernel<<<NBLK, 256, 0, stream>>>(cntI, NSEG, bsum);
    scan_top_kernel<<<1, 256, 0, stream>>>(bsum, NBLK, boff, off, NSEG);
    scan_final_kernel<<<NBLK, 256, 0, stream>>>(cntI, NSEG, boff, off);
    hipMemcpyAsync(cursor, off, (size_t)NSEG * 4, hipMemcpyDeviceToDevice, stream);
    reorder_kernel<<<(E + 255) / 256, 256, 0, stream>>>(srcp, dstp, et, cursor, srt, E);

    // ---- weights (combined per-layer BT: 16 relations + root) ----
    weightsT_kernel<<<(R_ * DIN1 * DHID + 255) / 256, 256, 0, stream>>>(comp1, basis1, BT1, DIN1, DHID);
    weightsT_kernel<<<(R_ * DHID * DOUT2 + 255) / 256, 256, 0, stream>>>(comp2, basis2, BT2, DHID, DOUT2);
    rootT_kernel<<<(DIN1 * DHID + 255) / 256, 256, 0, stream>>>(root1, BT1, DIN1, DHID);
    rootT_kernel<<<(DHID * DOUT2 + 255) / 256, 256, 0, stream>>>(root2, BT2, DHID, DOUT2);

    // ---- two fused RGCN layers + classifier ----
    const int gGrid = (N + 31) / 32;
    rgcn_gemm_kernel<DHID, true><<<gGrid, 256, 0, stream>>>(xbf,  off, srt, BT1, bias1, h1bf, N, 1);
    rgcn_gemm_kernel<DOUT2, false><<<gGrid, 256, 0, stream>>>(h1bf, off, srt, BT2, bias2, h2, N, 0);
    classifier_kernel<<<(N + 31) / 32, 256, 0, stream>>>(h2, wc, bc, out, N);
}

// Round 6
// 498.821 us; speedup vs baseline: 7.8318x; 1.2357x over previous
//
#include <hip/hip_runtime.h>

#define R_    16
#define NBAS  30
#define DIN1  128
#define DHID  128
#define DOUT2 64
#define DADR  400
#define KCH   128              // feature width of both layer inputs
#define LDB   ((R_ + 1) * 128) // combined weight row length (16 relations + root)

typedef __attribute__((ext_vector_type(8))) short bf16x8;
typedef __attribute__((ext_vector_type(4))) float f32x4;

__device__ __forceinline__ short f2bf(float f) {
    unsigned u = __float_as_uint(f);
    u += 0x7fffu + ((u >> 16) & 1u);   // round-to-nearest-even
    return (short)(u >> 16);
}
__device__ __forceinline__ float bf2f(short s) {
    return __uint_as_float(((unsigned)(unsigned short)s) << 16);
}

// ---------------- f32 -> bf16 bulk convert ----------------
__global__ __launch_bounds__(256) void tobf_kernel(const float* __restrict__ in,
                                                   short* __restrict__ out, int n4) {
    int i = blockIdx.x * 256 + threadIdx.x;
    if (i >= n4) return;
    float4 v = ((const float4*)in)[i];
    short4 b = { f2bf(v.x), f2bf(v.y), f2bf(v.z), f2bf(v.w) };
    ((short4*)out)[i] = b;
}

// ---------------- int counts per (dst, relation) segment ----------------
__global__ __launch_bounds__(256) void count_kernel(const int* __restrict__ dst,
                                                    const int* __restrict__ ety,
                                                    int* __restrict__ cnt, int E) {
    int e = blockIdx.x * blockDim.x + threadIdx.x;
    if (e < E) atomicAdd(&cnt[dst[e] * R_ + ety[e]], 1);
}

// ---------------- 3-phase exclusive scan over nseg counts ----------------
#define SCAN_CHUNK 2048
#define SCAN_IT    8

__global__ __launch_bounds__(256) void scan_bsum_kernel(const int* __restrict__ cnt, int nseg,
                                                        int* __restrict__ bsum) {
    __shared__ int sd[256];
    int base = blockIdx.x * SCAN_CHUNK;
    int s = 0;
    #pragma unroll
    for (int j = 0; j < SCAN_IT; ++j) {
        int idx = base + j * 256 + threadIdx.x;
        if (idx < nseg) s += cnt[idx];
    }
    sd[threadIdx.x] = s;
    __syncthreads();
    for (int st = 128; st > 0; st >>= 1) {
        if (threadIdx.x < st) sd[threadIdx.x] += sd[threadIdx.x + st];
        __syncthreads();
    }
    if (threadIdx.x == 0) bsum[blockIdx.x] = sd[0];
}

__global__ __launch_bounds__(256) void scan_top_kernel(const int* __restrict__ bsum, int nblk,
                                                       int* __restrict__ boff,
                                                       int* __restrict__ off, int nseg) {
    if (nblk > 256) {
        if (threadIdx.x == 0) {
            int run = 0;
            for (int i = 0; i < nblk; ++i) { int t = bsum[i]; boff[i] = run; run += t; }
            off[nseg] = run;
        }
        return;
    }
    __shared__ int sd[256];
    int v = (threadIdx.x < nblk) ? bsum[threadIdx.x] : 0;
    sd[threadIdx.x] = v;
    __syncthreads();
    for (int st = 1; st < 256; st <<= 1) {
        int t = (threadIdx.x >= st) ? sd[threadIdx.x - st] : 0;
        __syncthreads();
        sd[threadIdx.x] += t;
        __syncthreads();
    }
    if (threadIdx.x < nblk) boff[threadIdx.x] = sd[threadIdx.x] - v;   // exclusive
    if (threadIdx.x == nblk - 1) off[nseg] = sd[threadIdx.x];          // total = E
}

__global__ __launch_bounds__(256) void scan_final_kernel(const int* __restrict__ cnt, int nseg,
                                                         const int* __restrict__ boff,
                                                         int* __restrict__ off,
                                                         int* __restrict__ cursor) {
    __shared__ int sd[256];
    int base = blockIdx.x * SCAN_CHUNK + threadIdx.x * SCAN_IT;
    int v[SCAN_IT];
    int s = 0;
    #pragma unroll
    for (int j = 0; j < SCAN_IT; ++j) {
        int idx = base + j;
        v[j] = (idx < nseg) ? cnt[idx] : 0;
        s += v[j];
    }
    sd[threadIdx.x] = s;
    __syncthreads();
    for (int st = 1; st < 256; st <<= 1) {
        int t = (threadIdx.x >= st) ? sd[threadIdx.x - st] : 0;
        __syncthreads();
        sd[threadIdx.x] += t;
        __syncthreads();
    }
    int run = boff[blockIdx.x] + sd[threadIdx.x] - s;   // exclusive prefix of this thread
    #pragma unroll
    for (int j = 0; j < SCAN_IT; ++j) {
        int idx = base + j;
        if (idx < nseg) { off[idx] = run; cursor[idx] = run; }
        run += v[j];
    }
}

// ---------------- bucket the source indices (CSR payload) ----------------
__global__ __launch_bounds__(256) void reorder_kernel(const int* __restrict__ src,
                                                      const int* __restrict__ dst,
                                                      const int* __restrict__ ety,
                                                      int* __restrict__ cursor,
                                                      int* __restrict__ srt, int E) {
    int e = blockIdx.x * blockDim.x + threadIdx.x;
    if (e >= E) return;
    int seg = dst[e] * R_ + ety[e];
    int pos = atomicAdd(&cursor[seg], 1);
    srt[pos] = src[e];
}

// ------- BT[o][r*DIN + i] = bf16( sum_b comp[r,b] * basis[b,i,o] ), ldb = LDB -------
__global__ __launch_bounds__(256) void weightsT_kernel(const float* __restrict__ comp,
                                                       const float* __restrict__ basis,
                                                       short* __restrict__ wT,
                                                       int DIN, int DOUT) {
    int idx = blockIdx.x * blockDim.x + threadIdx.x;
    int total = R_ * DIN * DOUT;
    if (idx >= total) return;
    int o = idx % DOUT;
    int i = (idx / DOUT) % DIN;
    int r = idx / (DOUT * DIN);
    float acc = 0.f;
    #pragma unroll 6
    for (int b = 0; b < NBAS; ++b)
        acc += comp[r * NBAS + b] * basis[((size_t)b * DIN + i) * DOUT + o];
    wT[(size_t)o * LDB + r * DIN + i] = f2bf(acc);
}

// ------- BT[o][R_*DIN + i] = bf16(root[i][o]) -------
__global__ __launch_bounds__(256) void rootT_kernel(const float* __restrict__ root,
                                                    short* __restrict__ wT,
                                                    int DIN, int DOUT) {
    int idx = blockIdx.x * blockDim.x + threadIdx.x;
    if (idx >= DIN * DOUT) return;
    int o = idx % DOUT;
    int i = idx / DOUT;
    wT[(size_t)o * LDB + R_ * DIN + i] = f2bf(root[(size_t)i * DOUT + o]);
}

// ------- segment mean aggregation: agg[(r*N + n)][j] = mean over bucket (n,r) of featbf[src][j]
//   one 32-lane group per segment; 8 segments per 256-thread block -------
__global__ __launch_bounds__(256) void agg_kernel(const short* __restrict__ featbf,
                                                  const int* __restrict__ off,
                                                  const int* __restrict__ srt,
                                                  short* __restrict__ agg,
                                                  int N, int NSEG) {
    int g = blockIdx.x * 8 + (threadIdx.x >> 5);
    if (g >= NSEG) return;
    int lane = threadIdx.x & 31;
    int beg = off[g], end = off[g + 1];
    float a0 = 0.f, a1 = 0.f, a2 = 0.f, a3 = 0.f;
    int p = beg;
    for (; p + 2 <= end; p += 2) {                 // 2 independent gathers in flight
        int s0 = srt[p], s1 = srt[p + 1];
        short4 v0 = ((const short4*)(featbf + (size_t)s0 * KCH))[lane];
        short4 v1 = ((const short4*)(featbf + (size_t)s1 * KCH))[lane];
        a0 += bf2f(v0.x) + bf2f(v1.x);
        a1 += bf2f(v0.y) + bf2f(v1.y);
        a2 += bf2f(v0.z) + bf2f(v1.z);
        a3 += bf2f(v0.w) + bf2f(v1.w);
    }
    if (p < end) {
        short4 v0 = ((const short4*)(featbf + (size_t)srt[p] * KCH))[lane];
        a0 += bf2f(v0.x); a1 += bf2f(v0.y); a2 += bf2f(v0.z); a3 += bf2f(v0.w);
    }
    int c = end - beg;
    float sc = 1.f / (float)(c > 1 ? c : 1);
    short4 o4 = { f2bf(a0 * sc), f2bf(a1 * sc), f2bf(a2 * sc), f2bf(a3 * sc) };
    int r = g & 15, n = g >> 4;
    ((short4*)(agg + ((size_t)r * N + n) * KCH))[lane] = o4;
}

// ------- dense MFMA GEMM over 17 K-chunks (16 agg relations + root input):
//   H[n][o] = relu?( sum_r agg_r[n]@W_r + feat[n]@root + bias ) -------
template<int BN, bool OUTBF>
__global__ __launch_bounds__(256)
void gemm_dense_kernel(const short* __restrict__ featbf,  // [N][128] bf16 (root chunk)
                       const short* __restrict__ agg,     // [16*N][128] bf16, chunk r at rows r*N
                       const short* __restrict__ BT,      // [BN][LDB] bf16
                       const float* __restrict__ bias,
                       void* __restrict__ Hout, int N, int relu)
{
    constexpr int BM = 64, BK = 128;
    constexpr int WGN = 2;
    constexpr int WM = 32;           // BM / WGM
    constexpr int WN = BN / WGN;     // 64 or 32
    constexpr int MR = 2;
    constexpr int NR = WN / 16;      // 4 or 2

    __shared__ short lA[BM * BK];
    __shared__ short lB[BN * BK];

    const int tid  = threadIdx.x;
    const int lane = tid & 63;
    const int wv   = tid >> 6;
    const int wr   = wv / WGN;
    const int wcc  = wv % WGN;
    const int nodeBase = blockIdx.x * BM;

    f32x4 acc[MR][NR];
    #pragma unroll
    for (int m = 0; m < MR; ++m)
        #pragma unroll
        for (int n = 0; n < NR; ++n)
            acc[m][n] = (f32x4){0.f, 0.f, 0.f, 0.f};

    const int t8  = tid & 15;    // 16B unit within 128-bf16 row
    const int r16 = tid >> 4;    // 16 rows per pass

    for (int r = 0; r <= R_; ++r) {
        // ---- A tile: 64 x 128 bf16, dense from agg chunk r (or root input) ----
        const short* Asrc = (r < R_) ? (agg + (size_t)r * N * KCH) : featbf;
        #pragma unroll
        for (int it = 0; it < 4; ++it) {
            int row  = it * 16 + r16;
            int grow = nodeBase + row;
            int4 v = {0, 0, 0, 0};
            if (grow < N) v = *(const int4*)(Asrc + (size_t)grow * KCH + t8 * 8);
            int byte = ((row * BK + t8 * 8) << 1) ^ ((row & 15) << 4);
            *(int4*)((char*)lA + byte) = v;
        }
        // ---- B tile: BN x 128 bf16 from combined BT ----
        #pragma unroll
        for (int o = r16; o < BN; o += 16) {
            int4 v = *(const int4*)(BT + (size_t)o * LDB + r * BK + t8 * 8);
            int byte = ((o * BK + t8 * 8) << 1) ^ ((o & 15) << 4);
            *(int4*)((char*)lB + byte) = v;
        }
        __syncthreads();

        #pragma unroll
        for (int kk = 0; kk < BK / 32; ++kk) {
            const int kpos = kk * 32 + (lane >> 4) * 8;
            bf16x8 af[MR], bfr[NR];
            #pragma unroll
            for (int m = 0; m < MR; ++m) {
                int row = wr * WM + m * 16 + (lane & 15);
                af[m] = *(const bf16x8*)((const char*)lA +
                         (((row * BK + kpos) << 1) ^ ((row & 15) << 4)));
            }
            #pragma unroll
            for (int n = 0; n < NR; ++n) {
                int col = wcc * WN + n * 16 + (lane & 15);
                bfr[n] = *(const bf16x8*)((const char*)lB +
                         (((col * BK + kpos) << 1) ^ ((col & 15) << 4)));
            }
            #pragma unroll
            for (int m = 0; m < MR; ++m)
                #pragma unroll
                for (int n = 0; n < NR; ++n)
                    acc[m][n] = __builtin_amdgcn_mfma_f32_16x16x32_bf16(
                        af[m], bfr[n], acc[m][n], 0, 0, 0);
        }
        __syncthreads();
    }

    // ---- epilogue: C/D layout row=(lane>>4)*4+i, col=lane&15 ----
    #pragma unroll
    for (int m = 0; m < MR; ++m)
        #pragma unroll
        for (int n = 0; n < NR; ++n)
            #pragma unroll
            for (int i = 0; i < 4; ++i) {
                int row  = wr * WM + m * 16 + ((lane >> 4) << 2) + i;
                int col  = wcc * WN + n * 16 + (lane & 15);
                int grow = nodeBase + row;
                if (grow >= N) continue;
                float v = acc[m][n][i] + bias[col];
                if (relu) v = fmaxf(v, 0.f);
                if (OUTBF) ((short*)Hout)[(size_t)grow * BN + col] = f2bf(v);
                else       ((float*)Hout)[(size_t)grow * BN + col] = v;
            }
}

// ------- classifier: out[n][a..a+3] = h[n][:] @ wc[:][a..a+3] + bc, float4 wc loads -------
__global__ __launch_bounds__(256)
void classifier_kernel(const float* __restrict__ h, const float* __restrict__ wc,
                       const float* __restrict__ bc, float* __restrict__ out, int N) {
    constexpr int NB = 32;
    constexpr int A4 = DADR / 4;   // 100
    __shared__ float lh[NB * DOUT2];
    const int nb  = blockIdx.x * NB;
    const int tid = threadIdx.x;
    for (int idx = tid; idx < NB * DOUT2; idx += 256) {
        int gn = nb + idx / DOUT2;
        lh[idx] = (gn < N) ? h[(size_t)gn * DOUT2 + (idx % DOUT2)] : 0.f;
    }
    __syncthreads();
    for (int idx = tid; idx < NB * A4; idx += 256) {
        int nl = idx / A4, a = (idx % A4) * 4;
        int gn = nb + nl;
        if (gn >= N) continue;
        const float* hr = lh + nl * DOUT2;
        float4 acc = *(const float4*)(bc + a);
        #pragma unroll 16
        for (int k = 0; k < DOUT2; ++k) {
            float hv = hr[k];
            float4 w = *(const float4*)(wc + k * DADR + a);
            acc.x += hv * w.x; acc.y += hv * w.y;
            acc.z += hv * w.z; acc.w += hv * w.w;
        }
        *(float4*)(out + (size_t)gn * DADR + a) = acc;
    }
}

static inline size_t align16(size_t x) { return (x + 15) & ~(size_t)15; }

extern "C" void kernel_launch(void* const* d_in, const int* in_sizes, int n_in,
                              void* d_out, int out_size, void* d_ws, size_t ws_size,
                              hipStream_t stream) {
    const float* x      = (const float*)d_in[0];
    const int*   ei     = (const int*)d_in[1];
    const int*   et     = (const int*)d_in[2];
    const float* comp1  = (const float*)d_in[3];
    const float* basis1 = (const float*)d_in[4];
    const float* root1  = (const float*)d_in[5];
    const float* bias1  = (const float*)d_in[6];
    const float* comp2  = (const float*)d_in[7];
    const float* basis2 = (const float*)d_in[8];
    const float* root2  = (const float*)d_in[9];
    const float* bias2  = (const float*)d_in[10];
    const float* wc     = (const float*)d_in[11];
    const float* bc     = (const float*)d_in[12];
    float* out = (float*)d_out;

    const int E = in_sizes[1] / 2;
    const int N = in_sizes[0] / DIN1;
    const int* srcp = ei;
    const int* dstp = ei + E;

    const int NSEG = N * R_;
    const int NBLK = (NSEG + SCAN_CHUNK - 1) / SCAN_CHUNK;

    char* ws = (char*)d_ws;
    size_t o = 0;
    int*   cntI   = (int*)(ws + o);   o = align16(o + (size_t)NSEG * 4);
    int*   off    = (int*)(ws + o);   o = align16(o + (size_t)(NSEG + 1) * 4);
    int*   cursor = (int*)(ws + o);   o = align16(o + (size_t)NSEG * 4);
    int*   bsum   = (int*)(ws + o);   o = align16(o + (size_t)NBLK * 4);
    int*   boff   = (int*)(ws + o);   o = align16(o + (size_t)NBLK * 4);
    int*   srt    = (int*)(ws + o);   o = align16(o + (size_t)E * 4);
    short* BT1    = (short*)(ws + o); o = align16(o + (size_t)DHID * LDB * 2);
    short* BT2    = (short*)(ws + o); o = align16(o + (size_t)DOUT2 * LDB * 2);
    short* xbf    = (short*)(ws + o); o = align16(o + (size_t)N * DIN1 * 2);
    short* h1bf   = (short*)(ws + o); o = align16(o + (size_t)N * DHID * 2);
    short* aggbuf = (short*)(ws + o); o = align16(o + (size_t)NSEG * KCH * 2);
    float* h2     = (float*)(ws + o);

    // ---- bf16 copy of x ----
    const int n4 = N * DIN1 / 4;
    tobf_kernel<<<(n4 + 255) / 256, 256, 0, stream>>>(x, xbf, n4);

    // ---- CSR build ----
    hipMemsetAsync(cntI, 0, (size_t)NSEG * 4, stream);
    count_kernel<<<(E + 255) / 256, 256, 0, stream>>>(dstp, et, cntI, E);
    scan_bsum_kernel<<<NBLK, 256, 0, stream>>>(cntI, NSEG, bsum);
    scan_top_kernel<<<1, 256, 0, stream>>>(bsum, NBLK, boff, off, NSEG);
    scan_final_kernel<<<NBLK, 256, 0, stream>>>(cntI, NSEG, boff, off, cursor);
    reorder_kernel<<<(E + 255) / 256, 256, 0, stream>>>(srcp, dstp, et, cursor, srt, E);

    // ---- weights (combined per-layer BT: 16 relations + root) ----
    weightsT_kernel<<<(R_ * DIN1 * DHID + 255) / 256, 256, 0, stream>>>(comp1, basis1, BT1, DIN1, DHID);
    weightsT_kernel<<<(R_ * DHID * DOUT2 + 255) / 256, 256, 0, stream>>>(comp2, basis2, BT2, DHID, DOUT2);
    rootT_kernel<<<(DIN1 * DHID + 255) / 256, 256, 0, stream>>>(root1, BT1, DIN1, DHID);
    rootT_kernel<<<(DHID * DOUT2 + 255) / 256, 256, 0, stream>>>(root2, BT2, DHID, DOUT2);

    // ---- layer 1: aggregate + GEMM ----
    const int aGrid = (NSEG + 7) / 8;
    const int gGrid = (N + 63) / 64;
    agg_kernel<<<aGrid, 256, 0, stream>>>(xbf, off, srt, aggbuf, N, NSEG);
    gemm_dense_kernel<DHID, true><<<gGrid, 256, 0, stream>>>(xbf, aggbuf, BT1, bias1, h1bf, N, 1);

    // ---- layer 2: aggregate + GEMM ----
    agg_kernel<<<aGrid, 256, 0, stream>>>(h1bf, off, srt, aggbuf, N, NSEG);
    gemm_dense_kernel<DOUT2, false><<<gGrid, 256, 0, stream>>>(h1bf, aggbuf, BT2, bias2, h2, N, 0);

    // ---- classifier ----
    classifier_kernel<<<(N + 31) / 32, 256, 0, stream>>>(h2, wc, bc, out, N);
}

// Round 7
// 414.225 us; speedup vs baseline: 9.4312x; 1.2042x over previous
//
#include <hip/hip_runtime.h>

#define R_    16
#define NBAS  30
#define DIN1  128
#define DHID  128
#define DOUT2 64
#define DADR  400
#define KCH   128              // feature width of both layer inputs
#define LDB   ((R_ + 1) * 128) // combined weight row length (16 relations + root)

typedef __attribute__((ext_vector_type(8))) short bf16x8;
typedef __attribute__((ext_vector_type(4))) float f32x4;

__device__ __forceinline__ short f2bf(float f) {
    unsigned u = __float_as_uint(f);
    u += 0x7fffu + ((u >> 16) & 1u);   // round-to-nearest-even
    return (short)(u >> 16);
}
__device__ __forceinline__ float bf2f(short s) {
    return __uint_as_float(((unsigned)(unsigned short)s) << 16);
}

// ---------------- f32 -> bf16 bulk convert ----------------
__global__ __launch_bounds__(256) void tobf_kernel(const float* __restrict__ in,
                                                   short* __restrict__ out, int n4) {
    int i = blockIdx.x * 256 + threadIdx.x;
    if (i >= n4) return;
    float4 v = ((const float4*)in)[i];
    short4 b = { f2bf(v.x), f2bf(v.y), f2bf(v.z), f2bf(v.w) };
    ((short4*)out)[i] = b;
}

// ---------------- int counts per (dst, relation) segment ----------------
__global__ __launch_bounds__(256) void count_kernel(const int* __restrict__ dst,
                                                    const int* __restrict__ ety,
                                                    int* __restrict__ cnt, int E) {
    int e = blockIdx.x * blockDim.x + threadIdx.x;
    if (e < E) atomicAdd(&cnt[dst[e] * R_ + ety[e]], 1);
}

// ---------------- 3-phase exclusive scan over nseg counts ----------------
#define SCAN_CHUNK 2048
#define SCAN_IT    8

__global__ __launch_bounds__(256) void scan_bsum_kernel(const int* __restrict__ cnt, int nseg,
                                                        int* __restrict__ bsum) {
    __shared__ int sd[256];
    int base = blockIdx.x * SCAN_CHUNK;
    int s = 0;
    #pragma unroll
    for (int j = 0; j < SCAN_IT; ++j) {
        int idx = base + j * 256 + threadIdx.x;
        if (idx < nseg) s += cnt[idx];
    }
    sd[threadIdx.x] = s;
    __syncthreads();
    for (int st = 128; st > 0; st >>= 1) {
        if (threadIdx.x < st) sd[threadIdx.x] += sd[threadIdx.x + st];
        __syncthreads();
    }
    if (threadIdx.x == 0) bsum[blockIdx.x] = sd[0];
}

__global__ __launch_bounds__(256) void scan_top_kernel(const int* __restrict__ bsum, int nblk,
                                                       int* __restrict__ boff,
                                                       int* __restrict__ off, int nseg) {
    if (nblk > 256) {
        if (threadIdx.x == 0) {
            int run = 0;
            for (int i = 0; i < nblk; ++i) { int t = bsum[i]; boff[i] = run; run += t; }
            off[nseg] = run;
        }
        return;
    }
    __shared__ int sd[256];
    int v = (threadIdx.x < nblk) ? bsum[threadIdx.x] : 0;
    sd[threadIdx.x] = v;
    __syncthreads();
    for (int st = 1; st < 256; st <<= 1) {
        int t = (threadIdx.x >= st) ? sd[threadIdx.x - st] : 0;
        __syncthreads();
        sd[threadIdx.x] += t;
        __syncthreads();
    }
    if (threadIdx.x < nblk) boff[threadIdx.x] = sd[threadIdx.x] - v;   // exclusive
    if (threadIdx.x == nblk - 1) off[nseg] = sd[threadIdx.x];          // total = E
}

__global__ __launch_bounds__(256) void scan_final_kernel(const int* __restrict__ cnt, int nseg,
                                                         const int* __restrict__ boff,
                                                         int* __restrict__ off,
                                                         int* __restrict__ cursor) {
    __shared__ int sd[256];
    int base = blockIdx.x * SCAN_CHUNK + threadIdx.x * SCAN_IT;
    int v[SCAN_IT];
    int s = 0;
    #pragma unroll
    for (int j = 0; j < SCAN_IT; ++j) {
        int idx = base + j;
        v[j] = (idx < nseg) ? cnt[idx] : 0;
        s += v[j];
    }
    sd[threadIdx.x] = s;
    __syncthreads();
    for (int st = 1; st < 256; st <<= 1) {
        int t = (threadIdx.x >= st) ? sd[threadIdx.x - st] : 0;
        __syncthreads();
        sd[threadIdx.x] += t;
        __syncthreads();
    }
    int run = boff[blockIdx.x] + sd[threadIdx.x] - s;   // exclusive prefix of this thread
    #pragma unroll
    for (int j = 0; j < SCAN_IT; ++j) {
        int idx = base + j;
        if (idx < nseg) { off[idx] = run; cursor[idx] = run; }
        run += v[j];
    }
}

// ---------------- bucket the source indices (CSR payload) ----------------
__global__ __launch_bounds__(256) void reorder_kernel(const int* __restrict__ src,
                                                      const int* __restrict__ dst,
                                                      const int* __restrict__ ety,
                                                      int* __restrict__ cursor,
                                                      int* __restrict__ srt, int E) {
    int e = blockIdx.x * blockDim.x + threadIdx.x;
    if (e >= E) return;
    int seg = dst[e] * R_ + ety[e];
    int pos = atomicAdd(&cursor[seg], 1);
    srt[pos] = src[e];
}

// ------- BT[o][r*DIN + i] = bf16( sum_b comp[r,b] * basis[b,i,o] ), ldb = LDB -------
__global__ __launch_bounds__(256) void weightsT_kernel(const float* __restrict__ comp,
                                                       const float* __restrict__ basis,
                                                       short* __restrict__ wT,
                                                       int DIN, int DOUT) {
    int idx = blockIdx.x * blockDim.x + threadIdx.x;
    int total = R_ * DIN * DOUT;
    if (idx >= total) return;
    int o = idx % DOUT;
    int i = (idx / DOUT) % DIN;
    int r = idx / (DOUT * DIN);
    float acc = 0.f;
    #pragma unroll 6
    for (int b = 0; b < NBAS; ++b)
        acc += comp[r * NBAS + b] * basis[((size_t)b * DIN + i) * DOUT + o];
    wT[(size_t)o * LDB + r * DIN + i] = f2bf(acc);
}

// ------- BT[o][R_*DIN + i] = bf16(root[i][o]) -------
__global__ __launch_bounds__(256) void rootT_kernel(const float* __restrict__ root,
                                                    short* __restrict__ wT,
                                                    int DIN, int DOUT) {
    int idx = blockIdx.x * blockDim.x + threadIdx.x;
    if (idx >= DIN * DOUT) return;
    int o = idx % DOUT;
    int i = idx / DOUT;
    wT[(size_t)o * LDB + R_ * DIN + i] = f2bf(root[(size_t)i * DOUT + o]);
}

// ------- wcT[a][k] = bf16(wc[k][a]) -------
__global__ __launch_bounds__(256) void wcT_kernel(const float* __restrict__ wc,
                                                  short* __restrict__ wcT) {
    int idx = blockIdx.x * blockDim.x + threadIdx.x;
    if (idx >= DOUT2 * DADR) return;
    int a = idx / DOUT2;
    int k = idx % DOUT2;
    wcT[(size_t)a * DOUT2 + k] = f2bf(wc[(size_t)k * DADR + a]);
}

// ------- segment mean aggregation: agg[(r*N + n)][j] = mean over bucket (n,r) of featbf[src][j]
//   one 32-lane group per segment; 8 segments per 256-thread block -------
__global__ __launch_bounds__(256) void agg_kernel(const short* __restrict__ featbf,
                                                  const int* __restrict__ off,
                                                  const int* __restrict__ srt,
                                                  short* __restrict__ agg,
                                                  int N, int NSEG) {
    int g = blockIdx.x * 8 + (threadIdx.x >> 5);
    if (g >= NSEG) return;
    int lane = threadIdx.x & 31;
    int beg = off[g], end = off[g + 1];
    float a0 = 0.f, a1 = 0.f, a2 = 0.f, a3 = 0.f;
    int p = beg;
    for (; p + 2 <= end; p += 2) {                 // 2 independent gathers in flight
        int s0 = srt[p], s1 = srt[p + 1];
        short4 v0 = ((const short4*)(featbf + (size_t)s0 * KCH))[lane];
        short4 v1 = ((const short4*)(featbf + (size_t)s1 * KCH))[lane];
        a0 += bf2f(v0.x) + bf2f(v1.x);
        a1 += bf2f(v0.y) + bf2f(v1.y);
        a2 += bf2f(v0.z) + bf2f(v1.z);
        a3 += bf2f(v0.w) + bf2f(v1.w);
    }
    if (p < end) {
        short4 v0 = ((const short4*)(featbf + (size_t)srt[p] * KCH))[lane];
        a0 += bf2f(v0.x); a1 += bf2f(v0.y); a2 += bf2f(v0.z); a3 += bf2f(v0.w);
    }
    int c = end - beg;
    float sc = 1.f / (float)(c > 1 ? c : 1);
    short4 o4 = { f2bf(a0 * sc), f2bf(a1 * sc), f2bf(a2 * sc), f2bf(a3 * sc) };
    int r = g & 15, n = g >> 4;
    ((short4*)(agg + ((size_t)r * N + n) * KCH))[lane] = o4;
}

// ------- dense MFMA GEMM over 17 K-chunks (16 agg relations + root input):
//   H[n][o] = relu?( sum_r agg_r[n]@W_r + feat[n]@root + bias ) -------
template<int BN, bool OUTBF>
__global__ __launch_bounds__(256)
void gemm_dense_kernel(const short* __restrict__ featbf,  // [N][128] bf16 (root chunk)
                       const short* __restrict__ agg,     // [16*N][128] bf16, chunk r at rows r*N
                       const short* __restrict__ BT,      // [BN][LDB] bf16
                       const float* __restrict__ bias,
                       void* __restrict__ Hout, int N, int relu)
{
    constexpr int BM = 64, BK = 128;
    constexpr int WGN = 2;
    constexpr int WM = 32;           // BM / WGM
    constexpr int WN = BN / WGN;     // 64 or 32
    constexpr int MR = 2;
    constexpr int NR = WN / 16;      // 4 or 2

    __shared__ short lA[BM * BK];
    __shared__ short lB[BN * BK];

    const int tid  = threadIdx.x;
    const int lane = tid & 63;
    const int wv   = tid >> 6;
    const int wr   = wv / WGN;
    const int wcc  = wv % WGN;
    const int nodeBase = blockIdx.x * BM;

    f32x4 acc[MR][NR];
    #pragma unroll
    for (int m = 0; m < MR; ++m)
        #pragma unroll
        for (int n = 0; n < NR; ++n)
            acc[m][n] = (f32x4){0.f, 0.f, 0.f, 0.f};

    const int t8  = tid & 15;    // 16B unit within 128-bf16 row
    const int r16 = tid >> 4;    // 16 rows per pass

    for (int r = 0; r <= R_; ++r) {
        // ---- A tile: 64 x 128 bf16, dense from agg chunk r (or root input) ----
        const short* Asrc = (r < R_) ? (agg + (size_t)r * N * KCH) : featbf;
        #pragma unroll
        for (int it = 0; it < 4; ++it) {
            int row  = it * 16 + r16;
            int grow = nodeBase + row;
            int4 v = {0, 0, 0, 0};
            if (grow < N) v = *(const int4*)(Asrc + (size_t)grow * KCH + t8 * 8);
            int byte = ((row * BK + t8 * 8) << 1) ^ ((row & 15) << 4);
            *(int4*)((char*)lA + byte) = v;
        }
        // ---- B tile: BN x 128 bf16 from combined BT ----
        #pragma unroll
        for (int o = r16; o < BN; o += 16) {
            int4 v = *(const int4*)(BT + (size_t)o * LDB + r * BK + t8 * 8);
            int byte = ((o * BK + t8 * 8) << 1) ^ ((o & 15) << 4);
            *(int4*)((char*)lB + byte) = v;
        }
        __syncthreads();

        #pragma unroll
        for (int kk = 0; kk < BK / 32; ++kk) {
            const int kpos = kk * 32 + (lane >> 4) * 8;
            bf16x8 af[MR], bfr[NR];
            #pragma unroll
            for (int m = 0; m < MR; ++m) {
                int row = wr * WM + m * 16 + (lane & 15);
                af[m] = *(const bf16x8*)((const char*)lA +
                         (((row * BK + kpos) << 1) ^ ((row & 15) << 4)));
            }
            #pragma unroll
            for (int n = 0; n < NR; ++n) {
                int col = wcc * WN + n * 16 + (lane & 15);
                bfr[n] = *(const bf16x8*)((const char*)lB +
                         (((col * BK + kpos) << 1) ^ ((col & 15) << 4)));
            }
            #pragma unroll
            for (int m = 0; m < MR; ++m)
                #pragma unroll
                for (int n = 0; n < NR; ++n)
                    acc[m][n] = __builtin_amdgcn_mfma_f32_16x16x32_bf16(
                        af[m], bfr[n], acc[m][n], 0, 0, 0);
        }
        __syncthreads();
    }

    // ---- epilogue: C/D layout row=(lane>>4)*4+i, col=lane&15 ----
    #pragma unroll
    for (int m = 0; m < MR; ++m)
        #pragma unroll
        for (int n = 0; n < NR; ++n)
            #pragma unroll
            for (int i = 0; i < 4; ++i) {
                int row  = wr * WM + m * 16 + ((lane >> 4) << 2) + i;
                int col  = wcc * WN + n * 16 + (lane & 15);
                int grow = nodeBase + row;
                if (grow >= N) continue;
                float v = acc[m][n][i] + bias[col];
                if (relu) v = fmaxf(v, 0.f);
                if (OUTBF) ((short*)Hout)[(size_t)grow * BN + col] = f2bf(v);
                else       ((float*)Hout)[(size_t)grow * BN + col] = v;
            }
}

// ------- classifier MFMA GEMM: out[n][a] = h2[n][:] @ wcT[a][:] + bc[a]
//   BM=128 rows (4 waves x 32), BN=80 cols (5x16), K=64 single pass -------
__global__ __launch_bounds__(256)
void classifier_gemm_kernel(const short* __restrict__ h2bf,   // [N][64] bf16
                            const short* __restrict__ wcT,    // [400][64] bf16
                            const float* __restrict__ bc,
                            float* __restrict__ out, int N)
{
    constexpr int BM = 128, BN = 80, BK = 64;
    constexpr int MR = 2, NR = 5;

    __shared__ short lA[BM * BK];
    __shared__ short lB[BN * BK];

    const int tid  = threadIdx.x;
    const int lane = tid & 63;
    const int wv   = tid >> 6;             // wave = row group (32 rows each)
    const int nodeBase = blockIdx.x * BM;
    const int colBase  = blockIdx.y * BN;

    const int t8  = tid & 7;     // 16B unit within 64-bf16 row (8 units)
    const int r32 = tid >> 3;    // 32 rows per pass

    // ---- A tile: 128 x 64 ----
    #pragma unroll
    for (int it = 0; it < 4; ++it) {
        int row  = it * 32 + r32;
        int grow = nodeBase + row;
        int4 v = {0, 0, 0, 0};
        if (grow < N) v = *(const int4*)(h2bf + (size_t)grow * DOUT2 + t8 * 8);
        int byte = ((row * BK + t8 * 8) << 1) ^ ((row & 7) << 4);
        *(int4*)((char*)lA + byte) = v;
    }
    // ---- B tile: 80 x 64 ----
    for (int o = r32; o < BN; o += 32) {
        int4 v = *(const int4*)(wcT + (size_t)(colBase + o) * DOUT2 + t8 * 8);
        int byte = ((o * BK + t8 * 8) << 1) ^ ((o & 7) << 4);
        *(int4*)((char*)lB + byte) = v;
    }
    __syncthreads();

    f32x4 acc[MR][NR];
    #pragma unroll
    for (int m = 0; m < MR; ++m)
        #pragma unroll
        for (int n = 0; n < NR; ++n)
            acc[m][n] = (f32x4){0.f, 0.f, 0.f, 0.f};

    #pragma unroll
    for (int kk = 0; kk < BK / 32; ++kk) {
        const int kpos = kk * 32 + (lane >> 4) * 8;
        bf16x8 af[MR], bfr[NR];
        #pragma unroll
        for (int m = 0; m < MR; ++m) {
            int row = wv * 32 + m * 16 + (lane & 15);
            af[m] = *(const bf16x8*)((const char*)lA +
                     (((row * BK + kpos) << 1) ^ ((row & 7) << 4)));
        }
        #pragma unroll
        for (int n = 0; n < NR; ++n) {
            int col = n * 16 + (lane & 15);
            bfr[n] = *(const bf16x8*)((const char*)lB +
                     (((col * BK + kpos) << 1) ^ ((col & 7) << 4)));
        }
        #pragma unroll
        for (int m = 0; m < MR; ++m)
            #pragma unroll
            for (int n = 0; n < NR; ++n)
                acc[m][n] = __builtin_amdgcn_mfma_f32_16x16x32_bf16(
                    af[m], bfr[n], acc[m][n], 0, 0, 0);
    }

    // ---- epilogue ----
    #pragma unroll
    for (int m = 0; m < MR; ++m)
        #pragma unroll
        for (int n = 0; n < NR; ++n)
            #pragma unroll
            for (int i = 0; i < 4; ++i) {
                int row  = wv * 32 + m * 16 + ((lane >> 4) << 2) + i;
                int col  = n * 16 + (lane & 15);
                int grow = nodeBase + row;
                if (grow >= N) continue;
                int gcol = colBase + col;
                out[(size_t)grow * DADR + gcol] = acc[m][n][i] + bc[gcol];
            }
}

static inline size_t align16(size_t x) { return (x + 15) & ~(size_t)15; }

extern "C" void kernel_launch(void* const* d_in, const int* in_sizes, int n_in,
                              void* d_out, int out_size, void* d_ws, size_t ws_size,
                              hipStream_t stream) {
    const float* x      = (const float*)d_in[0];
    const int*   ei     = (const int*)d_in[1];
    const int*   et     = (const int*)d_in[2];
    const float* comp1  = (const float*)d_in[3];
    const float* basis1 = (const float*)d_in[4];
    const float* root1  = (const float*)d_in[5];
    const float* bias1  = (const float*)d_in[6];
    const float* comp2  = (const float*)d_in[7];
    const float* basis2 = (const float*)d_in[8];
    const float* root2  = (const float*)d_in[9];
    const float* bias2  = (const float*)d_in[10];
    const float* wc     = (const float*)d_in[11];
    const float* bc     = (const float*)d_in[12];
    float* out = (float*)d_out;

    const int E = in_sizes[1] / 2;
    const int N = in_sizes[0] / DIN1;
    const int* srcp = ei;
    const int* dstp = ei + E;

    const int NSEG = N * R_;
    const int NBLK = (NSEG + SCAN_CHUNK - 1) / SCAN_CHUNK;

    char* ws = (char*)d_ws;
    size_t o = 0;
    int*   cntI   = (int*)(ws + o);   o = align16(o + (size_t)NSEG * 4);
    int*   off    = (int*)(ws + o);   o = align16(o + (size_t)(NSEG + 1) * 4);
    int*   cursor = (int*)(ws + o);   o = align16(o + (size_t)NSEG * 4);
    int*   bsum   = (int*)(ws + o);   o = align16(o + (size_t)NBLK * 4);
    int*   boff   = (int*)(ws + o);   o = align16(o + (size_t)NBLK * 4);
    int*   srt    = (int*)(ws + o);   o = align16(o + (size_t)E * 4);
    short* BT1    = (short*)(ws + o); o = align16(o + (size_t)DHID * LDB * 2);
    short* BT2    = (short*)(ws + o); o = align16(o + (size_t)DOUT2 * LDB * 2);
    short* wcTb   = (short*)(ws + o); o = align16(o + (size_t)DADR * DOUT2 * 2);
    short* xbf    = (short*)(ws + o); o = align16(o + (size_t)N * DIN1 * 2);
    short* h1bf   = (short*)(ws + o); o = align16(o + (size_t)N * DHID * 2);
    short* h2bf   = (short*)(ws + o); o = align16(o + (size_t)N * DOUT2 * 2);
    short* aggbuf = (short*)(ws + o); o = align16(o + (size_t)NSEG * KCH * 2);

    // ---- bf16 copy of x ----
    const int n4 = N * DIN1 / 4;
    tobf_kernel<<<(n4 + 255) / 256, 256, 0, stream>>>(x, xbf, n4);

    // ---- CSR build ----
    hipMemsetAsync(cntI, 0, (size_t)NSEG * 4, stream);
    count_kernel<<<(E + 255) / 256, 256, 0, stream>>>(dstp, et, cntI, E);
    scan_bsum_kernel<<<NBLK, 256, 0, stream>>>(cntI, NSEG, bsum);
    scan_top_kernel<<<1, 256, 0, stream>>>(bsum, NBLK, boff, off, NSEG);
    scan_final_kernel<<<NBLK, 256, 0, stream>>>(cntI, NSEG, boff, off, cursor);
    reorder_kernel<<<(E + 255) / 256, 256, 0, stream>>>(srcp, dstp, et, cursor, srt, E);

    // ---- weights ----
    weightsT_kernel<<<(R_ * DIN1 * DHID + 255) / 256, 256, 0, stream>>>(comp1, basis1, BT1, DIN1, DHID);
    weightsT_kernel<<<(R_ * DHID * DOUT2 + 255) / 256, 256, 0, stream>>>(comp2, basis2, BT2, DHID, DOUT2);
    rootT_kernel<<<(DIN1 * DHID + 255) / 256, 256, 0, stream>>>(root1, BT1, DIN1, DHID);
    rootT_kernel<<<(DHID * DOUT2 + 255) / 256, 256, 0, stream>>>(root2, BT2, DHID, DOUT2);
    wcT_kernel<<<(DOUT2 * DADR + 255) / 256, 256, 0, stream>>>(wc, wcTb);

    // ---- layer 1: aggregate + GEMM ----
    const int aGrid = (NSEG + 7) / 8;
    const int gGrid = (N + 63) / 64;
    agg_kernel<<<aGrid, 256, 0, stream>>>(xbf, off, srt, aggbuf, N, NSEG);
    gemm_dense_kernel<DHID, true><<<gGrid, 256, 0, stream>>>(xbf, aggbuf, BT1, bias1, h1bf, N, 1);

    // ---- layer 2: aggregate + GEMM (bf16 out for classifier) ----
    agg_kernel<<<aGrid, 256, 0, stream>>>(h1bf, off, srt, aggbuf, N, NSEG);
    gemm_dense_kernel<DOUT2, true><<<gGrid, 256, 0, stream>>>(h1bf, aggbuf, BT2, bias2, h2bf, N, 0);

    // ---- classifier (MFMA) ----
    dim3 cGrid((N + 127) / 128, DADR / 80);
    classifier_gemm_kernel<<<cGrid, 256, 0, stream>>>(h2bf, wcTb, bc, out, N);
}

// Round 8
// 411.881 us; speedup vs baseline: 9.4849x; 1.0057x over previous
//
#include <hip/hip_runtime.h>

#define R_    16
#define NBAS  30
#define DIN1  128
#define DHID  128
#define DOUT2 64
#define DADR  400
#define KCH   128              // feature width of both layer inputs
#define LDB   ((R_ + 1) * 128) // combined weight row length (16 relations + root)

typedef __attribute__((ext_vector_type(8))) short bf16x8;
typedef __attribute__((ext_vector_type(4))) float f32x4;

__device__ __forceinline__ short f2bf(float f) {
    unsigned u = __float_as_uint(f);
    u += 0x7fffu + ((u >> 16) & 1u);   // round-to-nearest-even
    return (short)(u >> 16);
}
__device__ __forceinline__ float bf2f(short s) {
    return __uint_as_float(((unsigned)(unsigned short)s) << 16);
}
__device__ __forceinline__ unsigned packbf(float lo, float hi) {
    return (unsigned)(unsigned short)f2bf(lo) | ((unsigned)(unsigned short)f2bf(hi) << 16);
}
__device__ __forceinline__ void addpk(float* a, int4 v) {
    const unsigned* u = (const unsigned*)&v;
    #pragma unroll
    for (int i = 0; i < 4; ++i) {
        a[2 * i]     += __uint_as_float(u[i] << 16);
        a[2 * i + 1] += __uint_as_float(u[i] & 0xffff0000u);
    }
}

// ---------------- f32 -> bf16 bulk convert ----------------
__global__ __launch_bounds__(256) void tobf_kernel(const float* __restrict__ in,
                                                   short* __restrict__ out, int n4) {
    int i = blockIdx.x * 256 + threadIdx.x;
    if (i >= n4) return;
    float4 v = ((const float4*)in)[i];
    short4 b = { f2bf(v.x), f2bf(v.y), f2bf(v.z), f2bf(v.w) };
    ((short4*)out)[i] = b;
}

// ---------------- int counts per (dst, relation) segment ----------------
__global__ __launch_bounds__(256) void count_kernel(const int* __restrict__ dst,
                                                    const int* __restrict__ ety,
                                                    int* __restrict__ cnt, int E) {
    int e = blockIdx.x * blockDim.x + threadIdx.x;
    if (e < E) atomicAdd(&cnt[dst[e] * R_ + ety[e]], 1);
}

// ---------------- 3-phase exclusive scan over nseg counts ----------------
#define SCAN_CHUNK 2048
#define SCAN_IT    8

__global__ __launch_bounds__(256) void scan_bsum_kernel(const int* __restrict__ cnt, int nseg,
                                                        int* __restrict__ bsum) {
    __shared__ int sd[256];
    int base = blockIdx.x * SCAN_CHUNK;
    int s = 0;
    #pragma unroll
    for (int j = 0; j < SCAN_IT; ++j) {
        int idx = base + j * 256 + threadIdx.x;
        if (idx < nseg) s += cnt[idx];
    }
    sd[threadIdx.x] = s;
    __syncthreads();
    for (int st = 128; st > 0; st >>= 1) {
        if (threadIdx.x < st) sd[threadIdx.x] += sd[threadIdx.x + st];
        __syncthreads();
    }
    if (threadIdx.x == 0) bsum[blockIdx.x] = sd[0];
}

__global__ __launch_bounds__(256) void scan_top_kernel(const int* __restrict__ bsum, int nblk,
                                                       int* __restrict__ boff,
                                                       int* __restrict__ off, int nseg) {
    if (nblk > 256) {
        if (threadIdx.x == 0) {
            int run = 0;
            for (int i = 0; i < nblk; ++i) { int t = bsum[i]; boff[i] = run; run += t; }
            off[nseg] = run;
        }
        return;
    }
    __shared__ int sd[256];
    int v = (threadIdx.x < nblk) ? bsum[threadIdx.x] : 0;
    sd[threadIdx.x] = v;
    __syncthreads();
    for (int st = 1; st < 256; st <<= 1) {
        int t = (threadIdx.x >= st) ? sd[threadIdx.x - st] : 0;
        __syncthreads();
        sd[threadIdx.x] += t;
        __syncthreads();
    }
    if (threadIdx.x < nblk) boff[threadIdx.x] = sd[threadIdx.x] - v;   // exclusive
    if (threadIdx.x == nblk - 1) off[nseg] = sd[threadIdx.x];          // total = E
}

__global__ __launch_bounds__(256) void scan_final_kernel(const int* __restrict__ cnt, int nseg,
                                                         const int* __restrict__ boff,
                                                         int* __restrict__ off,
                                                         int* __restrict__ cursor) {
    __shared__ int sd[256];
    int base = blockIdx.x * SCAN_CHUNK + threadIdx.x * SCAN_IT;
    int v[SCAN_IT];
    int s = 0;
    #pragma unroll
    for (int j = 0; j < SCAN_IT; ++j) {
        int idx = base + j;
        v[j] = (idx < nseg) ? cnt[idx] : 0;
        s += v[j];
    }
    sd[threadIdx.x] = s;
    __syncthreads();
    for (int st = 1; st < 256; st <<= 1) {
        int t = (threadIdx.x >= st) ? sd[threadIdx.x - st] : 0;
        __syncthreads();
        sd[threadIdx.x] += t;
        __syncthreads();
    }
    int run = boff[blockIdx.x] + sd[threadIdx.x] - s;   // exclusive prefix of this thread
    #pragma unroll
    for (int j = 0; j < SCAN_IT; ++j) {
        int idx = base + j;
        if (idx < nseg) { off[idx] = run; cursor[idx] = run; }
        run += v[j];
    }
}

// ---------------- bucket the source indices (CSR payload) ----------------
__global__ __launch_bounds__(256) void reorder_kernel(const int* __restrict__ src,
                                                      const int* __restrict__ dst,
                                                      const int* __restrict__ ety,
                                                      int* __restrict__ cursor,
                                                      int* __restrict__ srt, int E) {
    int e = blockIdx.x * blockDim.x + threadIdx.x;
    if (e >= E) return;
    int seg = dst[e] * R_ + ety[e];
    int pos = atomicAdd(&cursor[seg], 1);
    srt[pos] = src[e];
}

// ------- fused weight prep:
//   BT1[o][r*128+i]  = bf16(sum_b comp1[r,b]*basis1[b,i,o])    (o<128)
//   BT2[o][r*128+i]  = bf16(sum_b comp2[r,b]*basis2[b,i,o])    (o<64)
//   BT1[o][2048+i]   = bf16(root1[i][o]); BT2[o][2048+i] = bf16(root2[i][o])
//   wcT[a][k]        = bf16(wc[k][a]) -------
#define PREP1 (R_ * DIN1 * DHID)                    // 262144
#define PREP2 (PREP1 + R_ * DHID * DOUT2)           // +131072
#define PREP3 (PREP2 + DIN1 * DHID)                 // +16384
#define PREP4 (PREP3 + DHID * DOUT2)                // +8192
#define PREP5 (PREP4 + DADR * DOUT2)                // +25600
__global__ __launch_bounds__(256) void prep_kernel(const float* __restrict__ comp1,
                                                   const float* __restrict__ basis1,
                                                   const float* __restrict__ root1,
                                                   const float* __restrict__ comp2,
                                                   const float* __restrict__ basis2,
                                                   const float* __restrict__ root2,
                                                   const float* __restrict__ wc,
                                                   short* __restrict__ BT1,
                                                   short* __restrict__ BT2,
                                                   short* __restrict__ wcT) {
    int idx = blockIdx.x * 256 + threadIdx.x;
    if (idx < PREP1) {
        int o = idx % DHID, i = (idx / DHID) % DIN1, r = idx / (DHID * DIN1);
        float acc = 0.f;
        #pragma unroll 6
        for (int b = 0; b < NBAS; ++b)
            acc += comp1[r * NBAS + b] * basis1[((size_t)b * DIN1 + i) * DHID + o];
        BT1[(size_t)o * LDB + r * DIN1 + i] = f2bf(acc);
    } else if (idx < PREP2) {
        int t = idx - PREP1;
        int o = t % DOUT2, i = (t / DOUT2) % DHID, r = t / (DOUT2 * DHID);
        float acc = 0.f;
        #pragma unroll 6
        for (int b = 0; b < NBAS; ++b)
            acc += comp2[r * NBAS + b] * basis2[((size_t)b * DHID + i) * DOUT2 + o];
        BT2[(size_t)o * LDB + r * DHID + i] = f2bf(acc);
    } else if (idx < PREP3) {
        int t = idx - PREP2;
        int o = t % DHID, i = t / DHID;
        BT1[(size_t)o * LDB + R_ * DIN1 + i] = f2bf(root1[(size_t)i * DHID + o]);
    } else if (idx < PREP4) {
        int t = idx - PREP3;
        int o = t % DOUT2, i = t / DOUT2;
        BT2[(size_t)o * LDB + R_ * DHID + i] = f2bf(root2[(size_t)i * DOUT2 + o]);
    } else if (idx < PREP5) {
        int t = idx - PREP4;
        int a = t / DOUT2, k = t % DOUT2;
        wcT[(size_t)a * DOUT2 + k] = f2bf(wc[(size_t)k * DADR + a]);
    }
}

// ------- segment mean aggregation: agg[(r*N + n)][j] = mean over bucket (n,r) of featbf[src][j]
//   one 16-lane group per segment (int4 = 8 channels per lane); 16 segments per block -------
__global__ __launch_bounds__(256) void agg_kernel(const short* __restrict__ featbf,
                                                  const int* __restrict__ off,
                                                  const int* __restrict__ srt,
                                                  short* __restrict__ agg,
                                                  int N, int NSEG) {
    int g = blockIdx.x * 16 + (threadIdx.x >> 4);
    if (g >= NSEG) return;
    int lane = threadIdx.x & 15;
    int beg = off[g], end = off[g + 1];
    float a[8] = {0.f, 0.f, 0.f, 0.f, 0.f, 0.f, 0.f, 0.f};
    int p = beg;
    for (; p + 2 <= end; p += 2) {                 // 2 independent 16B gathers in flight
        int s0 = srt[p], s1 = srt[p + 1];
        int4 v0 = ((const int4*)(featbf + (size_t)s0 * KCH))[lane];
        int4 v1 = ((const int4*)(featbf + (size_t)s1 * KCH))[lane];
        addpk(a, v0);
        addpk(a, v1);
    }
    if (p < end) {
        int4 v0 = ((const int4*)(featbf + (size_t)srt[p] * KCH))[lane];
        addpk(a, v0);
    }
    int c = end - beg;
    float sc = 1.f / (float)(c > 1 ? c : 1);
    int4 o4;
    unsigned* ou = (unsigned*)&o4;
    #pragma unroll
    for (int i = 0; i < 4; ++i)
        ou[i] = packbf(a[2 * i] * sc, a[2 * i + 1] * sc);
    int r = g & 15, n = g >> 4;
    ((int4*)(agg + ((size_t)r * N + n) * KCH))[lane] = o4;
}

// ------- dense MFMA GEMM over 17 K-chunks (16 agg relations + root input),
//   register-prefetch pipeline: loads for chunk r+1 issue during chunk r's MFMA ----
template<int BN, bool OUTBF>
__global__ __launch_bounds__(256)
void gemm_dense_kernel(const short* __restrict__ featbf,  // [N][128] bf16 (root chunk)
                       const short* __restrict__ agg,     // [16*N][128] bf16, chunk r at rows r*N
                       const short* __restrict__ BT,      // [BN][LDB] bf16
                       const float* __restrict__ bias,
                       void* __restrict__ Hout, int N, int relu)
{
    constexpr int BM = 64, BK = 128;
    constexpr int WGN = 2;
    constexpr int WM = 32;           // BM / WGM
    constexpr int WN = BN / WGN;     // 64 or 32
    constexpr int MR = 2;
    constexpr int NR = WN / 16;      // 4 or 2
    constexpr int BL = BN / 16;      // B int4-loads per thread (8 or 4)

    __shared__ short lA[BM * BK];
    __shared__ short lB[BN * BK];

    const int tid  = threadIdx.x;
    const int lane = tid & 63;
    const int wv   = tid >> 6;
    const int wr   = wv / WGN;
    const int wcc  = wv % WGN;
    const int nodeBase = blockIdx.x * BM;

    const int t8  = tid & 15;    // 16B unit within 128-bf16 row
    const int r16 = tid >> 4;    // 16 rows per pass

    f32x4 acc[MR][NR];
    #pragma unroll
    for (int m = 0; m < MR; ++m)
        #pragma unroll
        for (int n = 0; n < NR; ++n)
            acc[m][n] = (f32x4){0.f, 0.f, 0.f, 0.f};

    int4 va[4], vb[BL];

    // ---- prologue: load chunk 0 ----
    {
        const short* Asrc = agg;   // r = 0
        #pragma unroll
        for (int it = 0; it < 4; ++it) {
            int grow = nodeBase + it * 16 + r16;
            va[it] = (grow < N) ? *(const int4*)(Asrc + (size_t)grow * KCH + t8 * 8)
                                : (int4){0, 0, 0, 0};
        }
        #pragma unroll
        for (int j = 0; j < BL; ++j) {
            int o = j * 16 + r16;
            vb[j] = *(const int4*)(BT + (size_t)o * LDB + t8 * 8);
        }
    }

    for (int r = 0; r <= R_; ++r) {
        if (r) __syncthreads();              // previous MFMA reads done
        // ---- write current chunk to LDS (swizzled) ----
        #pragma unroll
        for (int it = 0; it < 4; ++it) {
            int row = it * 16 + r16;
            int byte = ((row * BK + t8 * 8) << 1) ^ ((row & 15) << 4);
            *(int4*)((char*)lA + byte) = va[it];
        }
        #pragma unroll
        for (int j = 0; j < BL; ++j) {
            int o = j * 16 + r16;
            int byte = ((o * BK + t8 * 8) << 1) ^ ((o & 15) << 4);
            *(int4*)((char*)lB + byte) = vb[j];
        }
        __syncthreads();

        // ---- prefetch next chunk into registers (overlaps MFMA below) ----
        if (r < R_) {
            const short* Asrc = (r + 1 < R_) ? (agg + (size_t)(r + 1) * N * KCH) : featbf;
            #pragma unroll
            for (int it = 0; it < 4; ++it) {
                int grow = nodeBase + it * 16 + r16;
                va[it] = (grow < N) ? *(const int4*)(Asrc + (size_t)grow * KCH + t8 * 8)
                                    : (int4){0, 0, 0, 0};
            }
            #pragma unroll
            for (int j = 0; j < BL; ++j) {
                int o = j * 16 + r16;
                vb[j] = *(const int4*)(BT + (size_t)o * LDB + (r + 1) * BK + t8 * 8);
            }
        }

        // ---- MFMA on LDS chunk r ----
        #pragma unroll
        for (int kk = 0; kk < BK / 32; ++kk) {
            const int kpos = kk * 32 + (lane >> 4) * 8;
            bf16x8 af[MR], bfr[NR];
            #pragma unroll
            for (int m = 0; m < MR; ++m) {
                int row = wr * WM + m * 16 + (lane & 15);
                af[m] = *(const bf16x8*)((const char*)lA +
                         (((row * BK + kpos) << 1) ^ ((row & 15) << 4)));
            }
            #pragma unroll
            for (int n = 0; n < NR; ++n) {
                int col = wcc * WN + n * 16 + (lane & 15);
                bfr[n] = *(const bf16x8*)((const char*)lB +
                         (((col * BK + kpos) << 1) ^ ((col & 15) << 4)));
            }
            #pragma unroll
            for (int m = 0; m < MR; ++m)
                #pragma unroll
                for (int n = 0; n < NR; ++n)
                    acc[m][n] = __builtin_amdgcn_mfma_f32_16x16x32_bf16(
                        af[m], bfr[n], acc[m][n], 0, 0, 0);
        }
    }

    // ---- epilogue: C/D layout row=(lane>>4)*4+i, col=lane&15 ----
    #pragma unroll
    for (int m = 0; m < MR; ++m)
        #pragma unroll
        for (int n = 0; n < NR; ++n)
            #pragma unroll
            for (int i = 0; i < 4; ++i) {
                int row  = wr * WM + m * 16 + ((lane >> 4) << 2) + i;
                int col  = wcc * WN + n * 16 + (lane & 15);
                int grow = nodeBase + row;
                if (grow >= N) continue;
                float v = acc[m][n][i] + bias[col];
                if (relu) v = fmaxf(v, 0.f);
                if (OUTBF) ((short*)Hout)[(size_t)grow * BN + col] = f2bf(v);
                else       ((float*)Hout)[(size_t)grow * BN + col] = v;
            }
}

// ------- classifier MFMA GEMM: out[n][a] = h2[n][:] @ wcT[a][:] + bc[a]
//   BM=128 rows (4 waves x 32), BN=80 cols (5x16), K=64 single pass -------
__global__ __launch_bounds__(256)
void classifier_gemm_kernel(const short* __restrict__ h2bf,   // [N][64] bf16
                            const short* __restrict__ wcT,    // [400][64] bf16
                            const float* __restrict__ bc,
                            float* __restrict__ out, int N)
{
    constexpr int BM = 128, BN = 80, BK = 64;
    constexpr int MR = 2, NR = 5;

    __shared__ short lA[BM * BK];
    __shared__ short lB[BN * BK];

    const int tid  = threadIdx.x;
    const int lane = tid & 63;
    const int wv   = tid >> 6;             // wave = row group (32 rows each)
    const int nodeBase = blockIdx.x * BM;
    const int colBase  = blockIdx.y * BN;

    const int t8  = tid & 7;     // 16B unit within 64-bf16 row (8 units)
    const int r32 = tid >> 3;    // 32 rows per pass

    // ---- A tile: 128 x 64 ----
    #pragma unroll
    for (int it = 0; it < 4; ++it) {
        int row  = it * 32 + r32;
        int grow = nodeBase + row;
        int4 v = {0, 0, 0, 0};
        if (grow < N) v = *(const int4*)(h2bf + (size_t)grow * DOUT2 + t8 * 8);
        int byte = ((row * BK + t8 * 8) << 1) ^ ((row & 7) << 4);
        *(int4*)((char*)lA + byte) = v;
    }
    // ---- B tile: 80 x 64 ----
    for (int o = r32; o < BN; o += 32) {
        int4 v = *(const int4*)(wcT + (size_t)(colBase + o) * DOUT2 + t8 * 8);
        int byte = ((o * BK + t8 * 8) << 1) ^ ((o & 7) << 4);
        *(int4*)((char*)lB + byte) = v;
    }
    __syncthreads();

    f32x4 acc[MR][NR];
    #pragma unroll
    for (int m = 0; m < MR; ++m)
        #pragma unroll
        for (int n = 0; n < NR; ++n)
            acc[m][n] = (f32x4){0.f, 0.f, 0.f, 0.f};

    #pragma unroll
    for (int kk = 0; kk < BK / 32; ++kk) {
        const int kpos = kk * 32 + (lane >> 4) * 8;
        bf16x8 af[MR], bfr[NR];
        #pragma unroll
        for (int m = 0; m < MR; ++m) {
            int row = wv * 32 + m * 16 + (lane & 15);
            af[m] = *(const bf16x8*)((const char*)lA +
                     (((row * BK + kpos) << 1) ^ ((row & 7) << 4)));
        }
        #pragma unroll
        for (int n = 0; n < NR; ++n) {
            int col = n * 16 + (lane & 15);
            bfr[n] = *(const bf16x8*)((const char*)lB +
                     (((col * BK + kpos) << 1) ^ ((col & 7) << 4)));
        }
        #pragma unroll
        for (int m = 0; m < MR; ++m)
            #pragma unroll
            for (int n = 0; n < NR; ++n)
                acc[m][n] = __builtin_amdgcn_mfma_f32_16x16x32_bf16(
                    af[m], bfr[n], acc[m][n], 0, 0, 0);
    }

    // ---- epilogue ----
    #pragma unroll
    for (int m = 0; m < MR; ++m)
        #pragma unroll
        for (int n = 0; n < NR; ++n)
            #pragma unroll
            for (int i = 0; i < 4; ++i) {
                int row  = wv * 32 + m * 16 + ((lane >> 4) << 2) + i;
                int col  = n * 16 + (lane & 15);
                int grow = nodeBase + row;
                if (grow >= N) continue;
                int gcol = colBase + col;
                out[(size_t)grow * DADR + gcol] = acc[m][n][i] + bc[gcol];
            }
}

static inline size_t align16(size_t x) { return (x + 15) & ~(size_t)15; }

extern "C" void kernel_launch(void* const* d_in, const int* in_sizes, int n_in,
                              void* d_out, int out_size, void* d_ws, size_t ws_size,
                              hipStream_t stream) {
    const float* x      = (const float*)d_in[0];
    const int*   ei     = (const int*)d_in[1];
    const int*   et     = (const int*)d_in[2];
    const float* comp1  = (const float*)d_in[3];
    const float* basis1 = (const float*)d_in[4];
    const float* root1  = (const float*)d_in[5];
    const float* bias1  = (const float*)d_in[6];
    const float* comp2  = (const float*)d_in[7];
    const float* basis2 = (const float*)d_in[8];
    const float* root2  = (const float*)d_in[9];
    const float* bias2  = (const float*)d_in[10];
    const float* wc     = (const float*)d_in[11];
    const float* bc     = (const float*)d_in[12];
    float* out = (float*)d_out;

    const int E = in_sizes[1] / 2;
    const int N = in_sizes[0] / DIN1;
    const int* srcp = ei;
    const int* dstp = ei + E;

    const int NSEG = N * R_;
    const int NBLK = (NSEG + SCAN_CHUNK - 1) / SCAN_CHUNK;

    char* ws = (char*)d_ws;
    size_t o = 0;
    int*   cntI   = (int*)(ws + o);   o = align16(o + (size_t)NSEG * 4);
    int*   off    = (int*)(ws + o);   o = align16(o + (size_t)(NSEG + 1) * 4);
    int*   cursor = (int*)(ws + o);   o = align16(o + (size_t)NSEG * 4);
    int*   bsum   = (int*)(ws + o);   o = align16(o + (size_t)NBLK * 4);
    int*   boff   = (int*)(ws + o);   o = align16(o + (size_t)NBLK * 4);
    int*   srt    = (int*)(ws + o);   o = align16(o + (size_t)E * 4);
    short* BT1    = (short*)(ws + o); o = align16(o + (size_t)DHID * LDB * 2);
    short* BT2    = (short*)(ws + o); o = align16(o + (size_t)DOUT2 * LDB * 2);
    short* wcTb   = (short*)(ws + o); o = align16(o + (size_t)DADR * DOUT2 * 2);
    short* xbf    = (short*)(ws + o); o = align16(o + (size_t)N * DIN1 * 2);
    short* h1bf   = (short*)(ws + o); o = align16(o + (size_t)N * DHID * 2);
    short* h2bf   = (short*)(ws + o); o = align16(o + (size_t)N * DOUT2 * 2);
    short* aggbuf = (short*)(ws + o); o = align16(o + (size_t)NSEG * KCH * 2);

    // ---- bf16 copy of x ----
    const int n4 = N * DIN1 / 4;
    tobf_kernel<<<(n4 + 255) / 256, 256, 0, stream>>>(x, xbf, n4);

    // ---- CSR build ----
    hipMemsetAsync(cntI, 0, (size_t)NSEG * 4, stream);
    count_kernel<<<(E + 255) / 256, 256, 0, stream>>>(dstp, et, cntI, E);
    scan_bsum_kernel<<<NBLK, 256, 0, stream>>>(cntI, NSEG, bsum);
    scan_top_kernel<<<1, 256, 0, stream>>>(bsum, NBLK, boff, off, NSEG);
    scan_final_kernel<<<NBLK, 256, 0, stream>>>(cntI, NSEG, boff, off, cursor);
    reorder_kernel<<<(E + 255) / 256, 256, 0, stream>>>(srcp, dstp, et, cursor, srt, E);

    // ---- weights (fused prep) ----
    prep_kernel<<<(PREP5 + 255) / 256, 256, 0, stream>>>(comp1, basis1, root1,
                                                         comp2, basis2, root2, wc,
                                                         BT1, BT2, wcTb);

    // ---- layer 1: aggregate + GEMM ----
    const int aGrid = (NSEG + 15) / 16;
    const int gGrid = (N + 63) / 64;
    agg_kernel<<<aGrid, 256, 0, stream>>>(xbf, off, srt, aggbuf, N, NSEG);
    gemm_dense_kernel<DHID, true><<<gGrid, 256, 0, stream>>>(xbf, aggbuf, BT1, bias1, h1bf, N, 1);

    // ---- layer 2: aggregate + GEMM (bf16 out for classifier) ----
    agg_kernel<<<aGrid, 256, 0, stream>>>(h1bf, off, srt, aggbuf, N, NSEG);
    gemm_dense_kernel<DOUT2, true><<<gGrid, 256, 0, stream>>>(h1bf, aggbuf, BT2, bias2, h2bf, N, 0);

    // ---- classifier (MFMA) ----
    dim3 cGrid((N + 127) / 128, DADR / 80);
    classifier_gemm_kernel<<<cGrid, 256, 0, stream>>>(h2bf, wcTb, bc, out, N);
}